// Round 21
// baseline (246.958 us; speedup 1.0000x reference)
//
#include <hip/hip_runtime.h>
#include <hip/hip_fp16.h>
#include <math.h>

#define NNODES (128*2048)
#define NEDGES (NNODES*8)
#define NPG 2048
#define EPG (NPG*8)
#define HPG (EPG/2)          // 8192 edges per partition
#define NGRAPH 128
#define KSEL1 1639
#define KSEL2 1312

__device__ __forceinline__ unsigned packh2(float a, float b) {
    __half2 h = __floats2half2_rn(a, b);
    return *reinterpret_cast<unsigned*>(&h);
}
__device__ __forceinline__ float2 unph2(unsigned u) {
    __half2 h = *reinterpret_cast<__half2*>(&u);
    return __half22float2(h);
}
__device__ __forceinline__ unsigned wscan_u(unsigned v, int lane) {
    #pragma unroll
    for (int off = 1; off < 64; off <<= 1) {
        unsigned n = __shfl_up(v, off);
        if (lane >= off) v += n;
    }
    return v;
}
__device__ __forceinline__ int wscan_i(int v, int lane) {
    #pragma unroll
    for (int off = 1; off < 64; off <<= 1) {
        int n = __shfl_up(v, off);
        if (lane >= off) v += n;
    }
    return v;
}

// ---------- partitioned CSR build: 2 WGs per graph, wave-scan ----------
// Placement order within a bucket is atomic-order-dependent; a deterministic
// insertion-sort post-pass (key = (src, ew-bits)) canonicalizes each bucket
// so every launch produces bitwise-identical edge_sorted (harness requires
// replay-deterministic outputs; fp summation order must not vary).
__global__ __launch_bounds__(1024) void k_csr(
    const int* __restrict__ src, const int* __restrict__ dst,
    const float* __restrict__ ew, int2* __restrict__ meta,
    int2* __restrict__ edge_sorted)
{
    __shared__ int cnt[NPG];
    __shared__ int curs[NPG];
    __shared__ int wpart[16];
    int t = threadIdx.x;
    int lane = t & 63, wv = t >> 6;
    int bid = blockIdx.x;
    int g = bid >> 1, part = bid & 1;
    const int ebase = g * EPG + part * HPG;
    int ds[8], ss[8]; float wws[8];
    #pragma unroll
    for (int j=0;j<8;++j) {
        int idx = ebase + t + 1024*j;
        ds[j] = dst[idx] & (NPG-1);
        ss[j] = src[idx];
        wws[j] = ew[idx];
    }
    for (int i = t; i < NPG; i += 1024) cnt[i] = 0;
    __syncthreads();
    #pragma unroll
    for (int j=0;j<8;++j) atomicAdd(&cnt[ds[j]], 1);
    __syncthreads();
    int base = t * 2;
    int l0 = cnt[base], l1 = cnt[base+1];
    int s0 = l0 + l1;
    int sc = wscan_i(s0, lane);
    if (lane == 63) wpart[wv] = sc;
    __syncthreads();
    int b = 0;
    for (int i = 0; i < wv; ++i) b += wpart[i];
    int run = b + sc - s0;
    curs[base] = run; curs[base+1] = run + l0;
    __syncthreads();
    for (int i = t; i < NPG; i += 1024)
        meta[(size_t)part*NNODES + g*NPG + i] = make_int2(ebase + curs[i], cnt[i]);
    __syncthreads();
    #pragma unroll
    for (int j=0;j<8;++j) {
        int pos = atomicAdd(&curs[ds[j]], 1);
        edge_sorted[ebase + pos] = make_int2(ss[j], __float_as_int(wws[j]));
    }
    __syncthreads();
    // deterministic canonical order within each bucket (insertion sort)
    for (int i = t; i < NPG; i += 1024) {
        int cv = cnt[i];
        if (cv > 1) {
            int beg = ebase + curs[i] - cv;    // curs[i] is now start+cnt
            for (int a = 1; a < cv; ++a) {
                int2 key = edge_sorted[beg + a];
                unsigned long long kk =
                    ((unsigned long long)(unsigned)key.x << 32) | (unsigned)key.y;
                int p = beg + a - 1;
                while (p >= beg) {
                    int2 cur = edge_sorted[p];
                    unsigned long long ck =
                        ((unsigned long long)(unsigned)cur.x << 32) | (unsigned)cur.y;
                    if (ck <= kk) break;
                    edge_sorted[p + 1] = cur;
                    --p;
                }
                edge_sorted[p + 1] = key;
            }
        }
    }
}

// ---------- conv1 front-end: k-split LDS staging, 4-node x 8-out tile ----------
// y and seed written as fp16 (rows = 64 B).
#define XP 36
__global__ __launch_bounds__(256, 4) void k_gemm64(
    const float* __restrict__ x, const float* __restrict__ Wrel,
    const float* __restrict__ Wroot, const float* __restrict__ b,
    unsigned char* __restrict__ yb, unsigned char* __restrict__ seedb)
{
    __shared__ float xs[128*XP];       // 18.4 KB (one 32-col half)
    __shared__ float wcat[64*64];      // 16 KB
    __shared__ float bb[32];
    int t = threadIdx.x;
    for (int i = t; i < 64*64; i += 256) {
        int k = i >> 6, j = i & 63;
        wcat[i] = (j < 32) ? Wrel[k*32 + j] : Wroot[k*32 + (j-32)];
    }
    if (t < 32) bb[t] = b[t];
    size_t nb = (size_t)blockIdx.x * 128;
    int q = t >> 5, ng = t & 31;
    float acc[4][8];
    #pragma unroll
    for (int i=0;i<4;++i)
        #pragma unroll
        for (int j=0;j<8;++j) acc[i][j]=0.f;
    for (int half = 0; half < 2; ++half) {
        __syncthreads();                       // xs reuse (and wcat ready)
        const float* xg = x + nb*64 + half*32;
        for (int i = t; i < 128*8; i += 256) { // 128-B contiguous chunks/row
            int r = i >> 3, c = i & 7;
            *(float4*)(&xs[r*XP + c*4]) = *(const float4*)(xg + r*64 + c*4);
        }
        __syncthreads();
        int kb = half*32;
        #pragma unroll 2
        for (int k = 0; k < 32; k += 4) {
            float4 w0[4], w1[4];
            #pragma unroll
            for (int kk=0;kk<4;++kk) {
                w0[kk] = *(const float4*)(&wcat[(kb+k+kk)*64 + q*8]);
                w1[kk] = *(const float4*)(&wcat[(kb+k+kk)*64 + q*8 + 4]);
            }
            #pragma unroll
            for (int i=0;i<4;++i) {
                float4 xv = *(const float4*)(&xs[(ng + i*32)*XP + k]);
                float xvv[4] = {xv.x, xv.y, xv.z, xv.w};
                #pragma unroll
                for (int kk=0;kk<4;++kk) {
                    acc[i][0]=fmaf(xvv[kk], w0[kk].x, acc[i][0]);
                    acc[i][1]=fmaf(xvv[kk], w0[kk].y, acc[i][1]);
                    acc[i][2]=fmaf(xvv[kk], w0[kk].z, acc[i][2]);
                    acc[i][3]=fmaf(xvv[kk], w0[kk].w, acc[i][3]);
                    acc[i][4]=fmaf(xvv[kk], w1[kk].x, acc[i][4]);
                    acc[i][5]=fmaf(xvv[kk], w1[kk].y, acc[i][5]);
                    acc[i][6]=fmaf(xvv[kk], w1[kk].z, acc[i][6]);
                    acc[i][7]=fmaf(xvv[kk], w1[kk].w, acc[i][7]);
                }
            }
        }
    }
    if (q < 4) {               // y outputs (fp16), wave-uniform branch
        #pragma unroll
        for (int i=0;i<4;++i) {
            uint4 pk;
            pk.x = packh2(acc[i][0], acc[i][1]);
            pk.y = packh2(acc[i][2], acc[i][3]);
            pk.z = packh2(acc[i][4], acc[i][5]);
            pk.w = packh2(acc[i][6], acc[i][7]);
            *(uint4*)(yb + (nb + ng + i*32)*64 + q*16) = pk;
        }
    } else {
        int qq = q - 4;
        float b0=bb[qq*8+0],b1=bb[qq*8+1],b2=bb[qq*8+2],b3=bb[qq*8+3];
        float b4=bb[qq*8+4],b5=bb[qq*8+5],b6=bb[qq*8+6],b7=bb[qq*8+7];
        #pragma unroll
        for (int i=0;i<4;++i) {
            uint4 pk;
            pk.x = packh2(acc[i][0]+b0, acc[i][1]+b1);
            pk.y = packh2(acc[i][2]+b2, acc[i][3]+b3);
            pk.z = packh2(acc[i][4]+b4, acc[i][5]+b5);
            pk.w = packh2(acc[i][6]+b6, acc[i][7]+b7);
            *(uint4*)(seedb + (nb + ng + i*32)*64 + qq*16) = pk;
        }
    }
}

// ---------- conv2 front-end: h fp16 staged to fp32 LDS, ts folded; y/seed fp16 ----------
__global__ __launch_bounds__(256, 4) void k_gemm32(
    const unsigned char* __restrict__ hb, const float* __restrict__ ts,
    const float* __restrict__ Wrel, const float* __restrict__ Wroot,
    const float* __restrict__ b, unsigned char* __restrict__ yb,
    unsigned char* __restrict__ seedb)
{
    __shared__ float xs[128*XP];       // 18.4 KB
    __shared__ float wcat[32*64];      // 8 KB
    __shared__ float bb[32];
    int t = threadIdx.x;
    for (int i = t; i < 32*64; i += 256) {
        int k = i >> 6, j = i & 63;
        wcat[i] = (j < 32) ? Wrel[k*32 + j] : Wroot[k*32 + (j-32)];
    }
    if (t < 32) bb[t] = b[t];
    size_t nb = (size_t)blockIdx.x * 128;
    const unsigned char* hg = hb + nb * 64;
    for (int i = t; i < 128*4; i += 256) {     // uint4 = 8 halfs
        int r = i >> 2, c = i & 3;
        uint4 u = *(const uint4*)(hg + r*64 + c*16);
        float2 p0=unph2(u.x), p1=unph2(u.y), p2=unph2(u.z), p3=unph2(u.w);
        float* dst = &xs[r*XP + c*8];
        *(float4*)(dst)   = make_float4(p0.x,p0.y,p1.x,p1.y);
        *(float4*)(dst+4) = make_float4(p2.x,p2.y,p3.x,p3.y);
    }
    __syncthreads();
    int q = t >> 5, ng = t & 31;
    float tsv[4];
    #pragma unroll
    for (int i=0;i<4;++i) tsv[i] = ts[nb + ng + i*32];
    float acc[4][8];
    #pragma unroll
    for (int i=0;i<4;++i)
        #pragma unroll
        for (int j=0;j<8;++j) acc[i][j]=0.f;
    #pragma unroll 2
    for (int k = 0; k < 32; k += 4) {
        float4 w0[4], w1[4];
        #pragma unroll
        for (int kk=0;kk<4;++kk) {
            w0[kk] = *(const float4*)(&wcat[(k+kk)*64 + q*8]);
            w1[kk] = *(const float4*)(&wcat[(k+kk)*64 + q*8 + 4]);
        }
        #pragma unroll
        for (int i=0;i<4;++i) {
            float4 xv = *(const float4*)(&xs[(ng + i*32)*XP + k]);
            float xvv[4] = {xv.x, xv.y, xv.z, xv.w};
            #pragma unroll
            for (int kk=0;kk<4;++kk) {
                acc[i][0]=fmaf(xvv[kk], w0[kk].x, acc[i][0]);
                acc[i][1]=fmaf(xvv[kk], w0[kk].y, acc[i][1]);
                acc[i][2]=fmaf(xvv[kk], w0[kk].z, acc[i][2]);
                acc[i][3]=fmaf(xvv[kk], w0[kk].w, acc[i][3]);
                acc[i][4]=fmaf(xvv[kk], w1[kk].x, acc[i][4]);
                acc[i][5]=fmaf(xvv[kk], w1[kk].y, acc[i][5]);
                acc[i][6]=fmaf(xvv[kk], w1[kk].z, acc[i][6]);
                acc[i][7]=fmaf(xvv[kk], w1[kk].w, acc[i][7]);
            }
        }
    }
    if (q < 4) {
        #pragma unroll
        for (int i=0;i<4;++i) {
            float sc = tsv[i];
            uint4 pk;
            pk.x = packh2(acc[i][0]*sc, acc[i][1]*sc);
            pk.y = packh2(acc[i][2]*sc, acc[i][3]*sc);
            pk.z = packh2(acc[i][4]*sc, acc[i][5]*sc);
            pk.w = packh2(acc[i][6]*sc, acc[i][7]*sc);
            *(uint4*)(yb + (nb + ng + i*32)*64 + q*16) = pk;
        }
    } else {
        int qq = q - 4;
        float b0=bb[qq*8+0],b1=bb[qq*8+1],b2=bb[qq*8+2],b3=bb[qq*8+3];
        float b4=bb[qq*8+4],b5=bb[qq*8+5],b6=bb[qq*8+6],b7=bb[qq*8+7];
        #pragma unroll
        for (int i=0;i<4;++i) {
            float sc = tsv[i];
            uint4 pk;
            pk.x = packh2(acc[i][0]*sc+b0, acc[i][1]*sc+b1);
            pk.y = packh2(acc[i][2]*sc+b2, acc[i][3]*sc+b3);
            pk.z = packh2(acc[i][4]*sc+b4, acc[i][5]*sc+b5);
            pk.w = packh2(acc[i][6]*sc+b6, acc[i][7]*sc+b7);
            *(uint4*)(seedb + (nb + ng + i*32)*64 + qq*16) = pk;
        }
    }
}

// ---------- fused gather + relu + score ----------
// 4 lanes per node, uint4 (16 B) loads; 2-way edge unroll, flattened part
// loop. XCD-aware block swizzle. (LDS staging of y was tried: SLOWER.)
__global__ __launch_bounds__(256) void k_gather(
    const int2* __restrict__ meta, const int2* __restrict__ edge_sorted,
    const unsigned char* __restrict__ yb, const float* __restrict__ pw,
    const int* __restrict__ mask, const unsigned char* __restrict__ seedb,
    unsigned char* __restrict__ hout, float* __restrict__ s)
{
    unsigned orig = blockIdx.x;
    unsigned nwg8 = gridDim.x >> 3;
    unsigned bid = (orig & 7u) * nwg8 + (orig >> 3);
    size_t tid = (size_t)bid * 256 + threadIdx.x;
    int node = (int)(tid >> 2);
    int q = (int)(tid & 3);                 // lane owns features 8q..8q+7
    float4 wv0 = ((const float4*)pw)[2*q];
    float4 wv1 = ((const float4*)pw)[2*q+1];
    float nn = wv0.x*wv0.x + wv0.y*wv0.y + wv0.z*wv0.z + wv0.w*wv0.w
             + wv1.x*wv1.x + wv1.y*wv1.y + wv1.z*wv1.z + wv1.w*wv1.w;
    nn += __shfl_xor(nn, 1); nn += __shfl_xor(nn, 2);
    float nrm = sqrtf(nn);
    bool valid = mask ? (mask[node] != 0) : true;
    float4 a0 = make_float4(0.f,0.f,0.f,0.f), a1 = make_float4(0.f,0.f,0.f,0.f);
    float4 b0 = make_float4(0.f,0.f,0.f,0.f), b1 = make_float4(0.f,0.f,0.f,0.f);
    if (valid) {
        uint4 su = *(const uint4*)(seedb + (size_t)node * 64 + q * 16);
        float2 s0 = unph2(su.x), s1 = unph2(su.y), s2 = unph2(su.z), s3 = unph2(su.w);
        a0 = make_float4(s0.x, s0.y, s1.x, s1.y);
        a1 = make_float4(s2.x, s2.y, s3.x, s3.y);
        #pragma unroll
        for (int p = 0; p < 2; ++p) {
            int2 m = meta[(size_t)p*NNODES + node];
            int e = m.x, end = m.x + m.y;
            for (; e + 1 < end; e += 2) {
                int2 ed0 = edge_sorted[e];
                int2 ed1 = edge_sorted[e+1];
                uint4 u0 = *(const uint4*)(yb + (size_t)ed0.x * 64 + q * 16);
                uint4 u1 = *(const uint4*)(yb + (size_t)ed1.x * 64 + q * 16);
                float w0 = __int_as_float(ed0.y);
                float w1 = __int_as_float(ed1.y);
                float2 p0, p1;
                p0 = unph2(u0.x); p1 = unph2(u0.y);
                a0.x = fmaf(p0.x, w0, a0.x); a0.y = fmaf(p0.y, w0, a0.y);
                a0.z = fmaf(p1.x, w0, a0.z); a0.w = fmaf(p1.y, w0, a0.w);
                p0 = unph2(u0.z); p1 = unph2(u0.w);
                a1.x = fmaf(p0.x, w0, a1.x); a1.y = fmaf(p0.y, w0, a1.y);
                a1.z = fmaf(p1.x, w0, a1.z); a1.w = fmaf(p1.y, w0, a1.w);
                p0 = unph2(u1.x); p1 = unph2(u1.y);
                b0.x = fmaf(p0.x, w1, b0.x); b0.y = fmaf(p0.y, w1, b0.y);
                b0.z = fmaf(p1.x, w1, b0.z); b0.w = fmaf(p1.y, w1, b0.w);
                p0 = unph2(u1.z); p1 = unph2(u1.w);
                b1.x = fmaf(p0.x, w1, b1.x); b1.y = fmaf(p0.y, w1, b1.y);
                b1.z = fmaf(p1.x, w1, b1.z); b1.w = fmaf(p1.y, w1, b1.w);
            }
            if (e < end) {
                int2 ed0 = edge_sorted[e];
                uint4 u0 = *(const uint4*)(yb + (size_t)ed0.x * 64 + q * 16);
                float w0 = __int_as_float(ed0.y);
                float2 p0, p1;
                p0 = unph2(u0.x); p1 = unph2(u0.y);
                a0.x = fmaf(p0.x, w0, a0.x); a0.y = fmaf(p0.y, w0, a0.y);
                a0.z = fmaf(p1.x, w0, a0.z); a0.w = fmaf(p1.y, w0, a0.w);
                p0 = unph2(u0.z); p1 = unph2(u0.w);
                a1.x = fmaf(p0.x, w0, a1.x); a1.y = fmaf(p0.y, w0, a1.y);
                a1.z = fmaf(p1.x, w0, a1.z); a1.w = fmaf(p1.y, w0, a1.w);
            }
        }
    }
    float hv0x = fmaxf(a0.x + b0.x, 0.f), hv0y = fmaxf(a0.y + b0.y, 0.f);
    float hv0z = fmaxf(a0.z + b0.z, 0.f), hv0w = fmaxf(a0.w + b0.w, 0.f);
    float hv1x = fmaxf(a1.x + b1.x, 0.f), hv1y = fmaxf(a1.y + b1.y, 0.f);
    float hv1z = fmaxf(a1.z + b1.z, 0.f), hv1w = fmaxf(a1.w + b1.w, 0.f);
    uint4 hw;
    hw.x = packh2(hv0x, hv0y);
    hw.y = packh2(hv0z, hv0w);
    hw.z = packh2(hv1x, hv1y);
    hw.w = packh2(hv1z, hv1w);
    *(uint4*)(hout + (size_t)node * 64 + q * 16) = hw;
    float dot = hv0x*wv0.x + hv0y*wv0.y + hv0z*wv0.z + hv0w*wv0.w
              + hv1x*wv1.x + hv1y*wv1.y + hv1z*wv1.z + hv1w*wv1.w;
    dot += __shfl_xor(dot, 1); dot += __shfl_xor(dot, 2);
    if (q == 0) s[node] = valid ? (dot / nrm) : -INFINITY;
}

// ---------- pooling: radix select with wave-level scans (few barriers) ----------
__global__ __launch_bounds__(1024) void k_pool(
    const float* __restrict__ s, const unsigned char* __restrict__ hb,
    float* __restrict__ ts_out, int* __restrict__ mask_out,
    float* __restrict__ xout, int ksel)
{
    __shared__ unsigned keys[NPG];
    __shared__ unsigned hist[256];
    __shared__ unsigned wpart[16];
    __shared__ unsigned char flag[NPG];
    __shared__ unsigned sh_bin, sh_krem;
    __shared__ float red[16*64];
    int t = threadIdx.x;
    int g = blockIdx.x;
    int lane = t & 63, wv = t >> 6;
    const float* sg = s + (size_t)g * NPG;
    for (int i = t; i < NPG; i += 1024) {
        unsigned u = __float_as_uint(sg[i]);
        keys[i] = (u & 0x80000000u) ? ~u : (u | 0x80000000u);
    }
    __syncthreads();
    unsigned prefix = 0u;
    unsigned krem = (unsigned)ksel;
    for (int level = 0; level < 4; ++level) {
        int shift = 24 - 8*level;
        if (t < 256) hist[t] = 0u;
        __syncthreads();
        unsigned pmask = level ? (0xFFFFFFFFu << (shift + 8)) : 0u;
        for (int i = t; i < NPG; i += 1024) {
            unsigned key = keys[i];
            if ((key & pmask) == prefix)
                atomicAdd(&hist[(key >> shift) & 0xFFu], 1u);
        }
        __syncthreads();
        unsigned vv = 0, sc = 0;
        if (t < 256) {
            vv = hist[255 - t];
            sc = wscan_u(vv, lane);
            if (lane == 63) wpart[wv] = sc;     // waves 0..3
        }
        __syncthreads();
        if (t < 256) {
            unsigned bsum = 0;
            for (int i = 0; i < wv; ++i) bsum += wpart[i];
            unsigned incl = bsum + sc;
            unsigned excl = incl - vv;
            if (incl >= krem && excl < krem) {
                sh_bin = (unsigned)(255 - t);
                sh_krem = krem - excl;
            }
        }
        __syncthreads();
        prefix |= (sh_bin << shift);
        krem = sh_krem;
    }
    __syncthreads();
    unsigned T = prefix;
    unsigned ties = krem;
    int base = t * 2;
    unsigned k0 = keys[base], k1 = keys[base+1];
    unsigned ceq = (k0 == T ? 1u : 0u) + (k1 == T ? 1u : 0u);
    unsigned sc2 = wscan_u(ceq, lane);
    if (lane == 63) wpart[wv] = sc2;            // waves 0..15
    __syncthreads();
    unsigned bsum2 = 0;
    for (int i = 0; i < wv; ++i) bsum2 += wpart[i];
    unsigned run = bsum2 + sc2 - ceq;
    {
        unsigned char f0, f1;
        if (k0 > T) f0 = 1;
        else if (k0 == T) { f0 = (run < ties) ? 1 : 0; run++; }
        else f0 = 0;
        if (k1 > T) f1 = 1;
        else if (k1 == T) { f1 = (run < ties) ? 1 : 0; run++; }
        else f1 = 0;
        flag[base] = f0; flag[base+1] = f1;
    }
    __syncthreads();

    float mx[32], sm[32];
    #pragma unroll
    for (int j=0;j<32;++j){ mx[j]=-INFINITY; sm[j]=0.f; }
    const unsigned char* hg = hb + (size_t)g * NPG * 64;
    for (int i = t; i < NPG; i += 1024) {
        bool sel = flag[i] != 0;
        float tsv = sel ? tanhf(sg[i]) : 0.f;
        const uint4* hr = (const uint4*)(hg + (size_t)i*64);
        #pragma unroll
        for (int c4=0;c4<4;++c4) {
            uint4 u = hr[c4];
            float2 p0=unph2(u.x), p1=unph2(u.y), p2=unph2(u.z), p3=unph2(u.w);
            float vals[8] = {p0.x,p0.y,p1.x,p1.y,p2.x,p2.y,p3.x,p3.y};
            #pragma unroll
            for (int j=0;j<8;++j) {
                float v = vals[j]*tsv;
                if (sel) { mx[c4*8+j]=fmaxf(mx[c4*8+j],v); sm[c4*8+j]+=v; }
            }
        }
        if (ts_out) ts_out[(size_t)g*NPG + i] = tsv;
        if (mask_out) mask_out[(size_t)g*NPG + i] = sel ? 1 : 0;
    }
    #pragma unroll
    for (int j=0;j<32;++j) {
        for (int off=32; off; off>>=1) {
            mx[j] = fmaxf(mx[j], __shfl_xor(mx[j], off));
            sm[j] += __shfl_xor(sm[j], off);
        }
    }
    if (lane == 0) {
        #pragma unroll
        for (int j=0;j<32;++j) { red[wv*64 + j] = mx[j]; red[wv*64 + 32 + j] = sm[j]; }
    }
    __syncthreads();
    if (t < 32) {
        float m = red[t], ss = red[32 + t];
        #pragma unroll
        for (int w=1; w<16; ++w) { m = fmaxf(m, red[w*64 + t]); ss += red[w*64 + 32 + t]; }
        xout[(size_t)g*64 + t] = m;
        xout[(size_t)g*64 + 32 + t] = ss / (float)ksel;
    }
}

__global__ __launch_bounds__(128) void k_readout(
    const float* __restrict__ x1, const float* __restrict__ x2,
    const float* __restrict__ l1W, const float* __restrict__ l1b,
    const float* __restrict__ l2W, const float* __restrict__ l2b,
    const float* __restrict__ l3W, const float* __restrict__ l3b,
    float* __restrict__ out)
{
    int g = threadIdx.x;
    float z[64];
    #pragma unroll
    for (int i=0;i<64;++i) z[i] = x1[g*64+i] + x2[g*64+i];
    float a1[32];
    for (int j=0;j<32;++j) {
        float acc = l1b[j];
        #pragma unroll
        for (int i=0;i<64;++i) acc = fmaf(z[i], l1W[i*32+j], acc);
        a1[j] = fmaxf(acc, 0.f);
    }
    float a2[16];
    for (int j=0;j<16;++j) {
        float acc = l2b[j];
        #pragma unroll
        for (int i=0;i<32;++i) acc = fmaf(a1[i], l2W[i*16+j], acc);
        a2[j] = fmaxf(acc, 0.f);
    }
    float o0 = l3b[0], o1 = l3b[1];
    #pragma unroll
    for (int i=0;i<16;++i) { o0 = fmaf(a2[i], l3W[i*2+0], o0); o1 = fmaf(a2[i], l3W[i*2+1], o1); }
    float m = fmaxf(o0, o1);
    float lse = m + logf(expf(o0-m) + expf(o1-m));
    out[g*2+0] = o0 - lse;
    out[g*2+1] = o1 - lse;
}

extern "C" void kernel_launch(void* const* d_in, const int* in_sizes, int n_in,
                              void* d_out, int out_size, void* d_ws, size_t ws_size,
                              hipStream_t stream)
{
    const float* x      = (const float*)d_in[0];
    const int*   ei     = (const int*)d_in[1];   // int32 (JAX x64 disabled)
    const float* eattr  = (const float*)d_in[2];
    const float* W1rel  = (const float*)d_in[4];
    const float* b1     = (const float*)d_in[5];
    const float* W1root = (const float*)d_in[6];
    const float* p1w    = (const float*)d_in[7];
    const float* W2rel  = (const float*)d_in[8];
    const float* b2     = (const float*)d_in[9];
    const float* W2root = (const float*)d_in[10];
    const float* p2w    = (const float*)d_in[11];
    const float* l1W    = (const float*)d_in[12];
    const float* l1b    = (const float*)d_in[13];
    const float* l2W    = (const float*)d_in[14];
    const float* l2b    = (const float*)d_in[15];
    const float* l3W    = (const float*)d_in[16];
    const float* l3b    = (const float*)d_in[17];
    const int* srcp = ei;
    const int* dstp = ei + NEDGES;

    unsigned char* yb    = (unsigned char*)d_ws;      // [NNODES,32] fp16 (16 MB)
    unsigned char* seedb = yb + (size_t)NNODES*64;    // [NNODES,32] fp16 (16 MB)
    unsigned char* hb    = seedb + (size_t)NNODES*64; // [NNODES,32] fp16 (16 MB)
    float* s1   = (float*)(hb + (size_t)NNODES*64);   // [NNODES]
    float* ts   = s1 + NNODES;                        // [NNODES]
    int*   mask = (int*)(ts + NNODES);                // [NNODES]
    float* x1   = (float*)(mask + NNODES);            // [128,64]
    float* x2   = x1 + NGRAPH*64;                     // [128,64]
    int2*  meta = (int2*)(x2 + NGRAPH*64);            // [2*NNODES] (start,count)
    int2*  edge_sorted = (int2*)(meta + 2*NNODES);    // [NEDGES] (src, ew)
    float* out  = (float*)d_out;

    dim3 b256(256);
    // ---- partitioned CSR: 2 WGs per graph (deterministic bucket order) ----
    k_csr<<<NGRAPH*2, dim3(1024), 0, stream>>>(srcp, dstp, eattr, meta,
                                               edge_sorted);
    // ---- conv1 front-end + gather/score (XCD-swizzled, 4 lanes/node) ----
    k_gemm64<<<NNODES/128, b256, 0, stream>>>(x, W1rel, W1root, b1, yb, seedb);
    k_gather<<<NNODES*4/256, b256, 0, stream>>>(meta, edge_sorted,
                                                yb, p1w, nullptr, seedb, hb, s1);
    // ---- pool1 (ts + mask + x1) ----
    k_pool<<<NGRAPH, dim3(1024), 0, stream>>>(s1, hb, ts, mask, x1, KSEL1);
    // ---- conv2 front-end (ts fused) + gather/score ----
    k_gemm32<<<NNODES/128, b256, 0, stream>>>(hb, ts, W2rel, W2root, b2, yb, seedb);
    k_gather<<<NNODES*4/256, b256, 0, stream>>>(meta, edge_sorted,
                                                yb, p2w, mask, seedb, hb, s1);
    // ---- pool2 (x2 only) ----
    k_pool<<<NGRAPH, dim3(1024), 0, stream>>>(s1, hb, nullptr, nullptr, x2, KSEL2);
    // ---- readout MLP ----
    k_readout<<<1, 128, 0, stream>>>(x1, x2, l1W, l1b, l2W, l2b, l3W, l3b, out);
}

// Round 22
// 210.961 us; speedup vs baseline: 1.1706x; 1.1706x over previous
//
#include <hip/hip_runtime.h>
#include <hip/hip_fp16.h>
#include <math.h>

#define NNODES (128*2048)
#define NEDGES (NNODES*8)
#define NPG 2048
#define EPG (NPG*8)
#define HPG (EPG/2)          // 8192 edges per partition
#define NGRAPH 128
#define KSEL1 1639
#define KSEL2 1312

__device__ __forceinline__ unsigned packh2(float a, float b) {
    __half2 h = __floats2half2_rn(a, b);
    return *reinterpret_cast<unsigned*>(&h);
}
__device__ __forceinline__ float2 unph2(unsigned u) {
    __half2 h = *reinterpret_cast<__half2*>(&u);
    return __half22float2(h);
}
__device__ __forceinline__ unsigned wscan_u(unsigned v, int lane) {
    #pragma unroll
    for (int off = 1; off < 64; off <<= 1) {
        unsigned n = __shfl_up(v, off);
        if (lane >= off) v += n;
    }
    return v;
}
__device__ __forceinline__ int wscan_i(int v, int lane) {
    #pragma unroll
    for (int off = 1; off < 64; off <<= 1) {
        int n = __shfl_up(v, off);
        if (lane >= off) v += n;
    }
    return v;
}

// ---------- partitioned CSR build, fully in LDS ----------
// 2 WGs per graph. Edge window (8192 x 8 B = 64 KB) is built and
// canonically sorted per bucket in LDS, then written out linearly.
// Canonical per-bucket order: ascending (src, ew-bits) -> bitwise
// deterministic edge_sorted on every launch (replay determinism).
__global__ __launch_bounds__(1024) void k_csr(
    const int* __restrict__ src, const int* __restrict__ dst,
    const float* __restrict__ ew, int2* __restrict__ meta,
    int2* __restrict__ edge_sorted)
{
    __shared__ int2 ebuf[HPG];     // 64 KB
    __shared__ int cnt[NPG];       // 8 KB
    __shared__ int curs[NPG];      // 8 KB
    __shared__ int wpart[16];
    int t = threadIdx.x;
    int lane = t & 63, wv = t >> 6;
    int bid = blockIdx.x;
    int g = bid >> 1, part = bid & 1;
    const int ebase = g * EPG + part * HPG;
    int ds[8], ss[8]; float wws[8];
    #pragma unroll
    for (int j=0;j<8;++j) {
        int idx = ebase + t + 1024*j;
        ds[j] = dst[idx] & (NPG-1);
        ss[j] = src[idx];
        wws[j] = ew[idx];
    }
    for (int i = t; i < NPG; i += 1024) cnt[i] = 0;
    __syncthreads();
    #pragma unroll
    for (int j=0;j<8;++j) atomicAdd(&cnt[ds[j]], 1);
    __syncthreads();
    int base = t * 2;
    int l0 = cnt[base], l1 = cnt[base+1];
    int s0 = l0 + l1;
    int sc = wscan_i(s0, lane);
    if (lane == 63) wpart[wv] = sc;
    __syncthreads();
    int b = 0;
    for (int i = 0; i < wv; ++i) b += wpart[i];
    int run = b + sc - s0;
    curs[base] = run; curs[base+1] = run + l0;   // partition-local offsets
    __syncthreads();
    for (int i = t; i < NPG; i += 1024)
        meta[(size_t)part*NNODES + g*NPG + i] = make_int2(ebase + curs[i], cnt[i]);
    __syncthreads();
    #pragma unroll
    for (int j=0;j<8;++j) {
        int pos = atomicAdd(&curs[ds[j]], 1);
        ebuf[pos] = make_int2(ss[j], __float_as_int(wws[j]));
    }
    __syncthreads();
    // canonical per-bucket order (insertion sort in LDS)
    for (int i = t; i < NPG; i += 1024) {
        int cv = cnt[i];
        if (cv > 1) {
            int beg = curs[i] - cv;              // curs[i] is now start+cnt
            for (int a = 1; a < cv; ++a) {
                int2 key = ebuf[beg + a];
                unsigned long long kk =
                    ((unsigned long long)(unsigned)key.x << 32) | (unsigned)key.y;
                int p = beg + a - 1;
                while (p >= beg) {
                    int2 cur = ebuf[p];
                    unsigned long long ck =
                        ((unsigned long long)(unsigned)cur.x << 32) | (unsigned)cur.y;
                    if (ck <= kk) break;
                    ebuf[p + 1] = cur;
                    --p;
                }
                ebuf[p + 1] = key;
            }
        }
    }
    __syncthreads();
    // coalesced linear write-out
    #pragma unroll
    for (int j=0;j<8;++j) {
        int i = t + 1024*j;
        edge_sorted[ebase + i] = ebuf[i];
    }
}

// ---------- conv1 front-end: k-split LDS staging, 4-node x 8-out tile ----------
// y and seed written as fp16 (rows = 64 B).
#define XP 36
__global__ __launch_bounds__(256, 4) void k_gemm64(
    const float* __restrict__ x, const float* __restrict__ Wrel,
    const float* __restrict__ Wroot, const float* __restrict__ b,
    unsigned char* __restrict__ yb, unsigned char* __restrict__ seedb)
{
    __shared__ float xs[128*XP];       // 18.4 KB (one 32-col half)
    __shared__ float wcat[64*64];      // 16 KB
    __shared__ float bb[32];
    int t = threadIdx.x;
    for (int i = t; i < 64*64; i += 256) {
        int k = i >> 6, j = i & 63;
        wcat[i] = (j < 32) ? Wrel[k*32 + j] : Wroot[k*32 + (j-32)];
    }
    if (t < 32) bb[t] = b[t];
    size_t nb = (size_t)blockIdx.x * 128;
    int q = t >> 5, ng = t & 31;
    float acc[4][8];
    #pragma unroll
    for (int i=0;i<4;++i)
        #pragma unroll
        for (int j=0;j<8;++j) acc[i][j]=0.f;
    for (int half = 0; half < 2; ++half) {
        __syncthreads();                       // xs reuse (and wcat ready)
        const float* xg = x + nb*64 + half*32;
        for (int i = t; i < 128*8; i += 256) { // 128-B contiguous chunks/row
            int r = i >> 3, c = i & 7;
            *(float4*)(&xs[r*XP + c*4]) = *(const float4*)(xg + r*64 + c*4);
        }
        __syncthreads();
        int kb = half*32;
        #pragma unroll 2
        for (int k = 0; k < 32; k += 4) {
            float4 w0[4], w1[4];
            #pragma unroll
            for (int kk=0;kk<4;++kk) {
                w0[kk] = *(const float4*)(&wcat[(kb+k+kk)*64 + q*8]);
                w1[kk] = *(const float4*)(&wcat[(kb+k+kk)*64 + q*8 + 4]);
            }
            #pragma unroll
            for (int i=0;i<4;++i) {
                float4 xv = *(const float4*)(&xs[(ng + i*32)*XP + k]);
                float xvv[4] = {xv.x, xv.y, xv.z, xv.w};
                #pragma unroll
                for (int kk=0;kk<4;++kk) {
                    acc[i][0]=fmaf(xvv[kk], w0[kk].x, acc[i][0]);
                    acc[i][1]=fmaf(xvv[kk], w0[kk].y, acc[i][1]);
                    acc[i][2]=fmaf(xvv[kk], w0[kk].z, acc[i][2]);
                    acc[i][3]=fmaf(xvv[kk], w0[kk].w, acc[i][3]);
                    acc[i][4]=fmaf(xvv[kk], w1[kk].x, acc[i][4]);
                    acc[i][5]=fmaf(xvv[kk], w1[kk].y, acc[i][5]);
                    acc[i][6]=fmaf(xvv[kk], w1[kk].z, acc[i][6]);
                    acc[i][7]=fmaf(xvv[kk], w1[kk].w, acc[i][7]);
                }
            }
        }
    }
    if (q < 4) {               // y outputs (fp16), wave-uniform branch
        #pragma unroll
        for (int i=0;i<4;++i) {
            uint4 pk;
            pk.x = packh2(acc[i][0], acc[i][1]);
            pk.y = packh2(acc[i][2], acc[i][3]);
            pk.z = packh2(acc[i][4], acc[i][5]);
            pk.w = packh2(acc[i][6], acc[i][7]);
            *(uint4*)(yb + (nb + ng + i*32)*64 + q*16) = pk;
        }
    } else {
        int qq = q - 4;
        float b0=bb[qq*8+0],b1=bb[qq*8+1],b2=bb[qq*8+2],b3=bb[qq*8+3];
        float b4=bb[qq*8+4],b5=bb[qq*8+5],b6=bb[qq*8+6],b7=bb[qq*8+7];
        #pragma unroll
        for (int i=0;i<4;++i) {
            uint4 pk;
            pk.x = packh2(acc[i][0]+b0, acc[i][1]+b1);
            pk.y = packh2(acc[i][2]+b2, acc[i][3]+b3);
            pk.z = packh2(acc[i][4]+b4, acc[i][5]+b5);
            pk.w = packh2(acc[i][6]+b6, acc[i][7]+b7);
            *(uint4*)(seedb + (nb + ng + i*32)*64 + qq*16) = pk;
        }
    }
}

// ---------- conv2 front-end: h fp16 staged to fp32 LDS, ts folded; y/seed fp16 ----------
__global__ __launch_bounds__(256, 4) void k_gemm32(
    const unsigned char* __restrict__ hb, const float* __restrict__ ts,
    const float* __restrict__ Wrel, const float* __restrict__ Wroot,
    const float* __restrict__ b, unsigned char* __restrict__ yb,
    unsigned char* __restrict__ seedb)
{
    __shared__ float xs[128*XP];       // 18.4 KB
    __shared__ float wcat[32*64];      // 8 KB
    __shared__ float bb[32];
    int t = threadIdx.x;
    for (int i = t; i < 32*64; i += 256) {
        int k = i >> 6, j = i & 63;
        wcat[i] = (j < 32) ? Wrel[k*32 + j] : Wroot[k*32 + (j-32)];
    }
    if (t < 32) bb[t] = b[t];
    size_t nb = (size_t)blockIdx.x * 128;
    const unsigned char* hg = hb + nb * 64;
    for (int i = t; i < 128*4; i += 256) {     // uint4 = 8 halfs
        int r = i >> 2, c = i & 3;
        uint4 u = *(const uint4*)(hg + r*64 + c*16);
        float2 p0=unph2(u.x), p1=unph2(u.y), p2=unph2(u.z), p3=unph2(u.w);
        float* dst = &xs[r*XP + c*8];
        *(float4*)(dst)   = make_float4(p0.x,p0.y,p1.x,p1.y);
        *(float4*)(dst+4) = make_float4(p2.x,p2.y,p3.x,p3.y);
    }
    __syncthreads();
    int q = t >> 5, ng = t & 31;
    float tsv[4];
    #pragma unroll
    for (int i=0;i<4;++i) tsv[i] = ts[nb + ng + i*32];
    float acc[4][8];
    #pragma unroll
    for (int i=0;i<4;++i)
        #pragma unroll
        for (int j=0;j<8;++j) acc[i][j]=0.f;
    #pragma unroll 2
    for (int k = 0; k < 32; k += 4) {
        float4 w0[4], w1[4];
        #pragma unroll
        for (int kk=0;kk<4;++kk) {
            w0[kk] = *(const float4*)(&wcat[(k+kk)*64 + q*8]);
            w1[kk] = *(const float4*)(&wcat[(k+kk)*64 + q*8 + 4]);
        }
        #pragma unroll
        for (int i=0;i<4;++i) {
            float4 xv = *(const float4*)(&xs[(ng + i*32)*XP + k]);
            float xvv[4] = {xv.x, xv.y, xv.z, xv.w};
            #pragma unroll
            for (int kk=0;kk<4;++kk) {
                acc[i][0]=fmaf(xvv[kk], w0[kk].x, acc[i][0]);
                acc[i][1]=fmaf(xvv[kk], w0[kk].y, acc[i][1]);
                acc[i][2]=fmaf(xvv[kk], w0[kk].z, acc[i][2]);
                acc[i][3]=fmaf(xvv[kk], w0[kk].w, acc[i][3]);
                acc[i][4]=fmaf(xvv[kk], w1[kk].x, acc[i][4]);
                acc[i][5]=fmaf(xvv[kk], w1[kk].y, acc[i][5]);
                acc[i][6]=fmaf(xvv[kk], w1[kk].z, acc[i][6]);
                acc[i][7]=fmaf(xvv[kk], w1[kk].w, acc[i][7]);
            }
        }
    }
    if (q < 4) {
        #pragma unroll
        for (int i=0;i<4;++i) {
            float sc = tsv[i];
            uint4 pk;
            pk.x = packh2(acc[i][0]*sc, acc[i][1]*sc);
            pk.y = packh2(acc[i][2]*sc, acc[i][3]*sc);
            pk.z = packh2(acc[i][4]*sc, acc[i][5]*sc);
            pk.w = packh2(acc[i][6]*sc, acc[i][7]*sc);
            *(uint4*)(yb + (nb + ng + i*32)*64 + q*16) = pk;
        }
    } else {
        int qq = q - 4;
        float b0=bb[qq*8+0],b1=bb[qq*8+1],b2=bb[qq*8+2],b3=bb[qq*8+3];
        float b4=bb[qq*8+4],b5=bb[qq*8+5],b6=bb[qq*8+6],b7=bb[qq*8+7];
        #pragma unroll
        for (int i=0;i<4;++i) {
            float sc = tsv[i];
            uint4 pk;
            pk.x = packh2(acc[i][0]*sc+b0, acc[i][1]*sc+b1);
            pk.y = packh2(acc[i][2]*sc+b2, acc[i][3]*sc+b3);
            pk.z = packh2(acc[i][4]*sc+b4, acc[i][5]*sc+b5);
            pk.w = packh2(acc[i][6]*sc+b6, acc[i][7]*sc+b7);
            *(uint4*)(seedb + (nb + ng + i*32)*64 + qq*16) = pk;
        }
    }
}

// ---------- fused gather + relu + score ----------
// 4 lanes per node, uint4 (16 B) loads; 2-way edge unroll, flattened part
// loop. XCD-aware block swizzle. (LDS staging of y was tried: SLOWER.)
__global__ __launch_bounds__(256) void k_gather(
    const int2* __restrict__ meta, const int2* __restrict__ edge_sorted,
    const unsigned char* __restrict__ yb, const float* __restrict__ pw,
    const int* __restrict__ mask, const unsigned char* __restrict__ seedb,
    unsigned char* __restrict__ hout, float* __restrict__ s)
{
    unsigned orig = blockIdx.x;
    unsigned nwg8 = gridDim.x >> 3;
    unsigned bid = (orig & 7u) * nwg8 + (orig >> 3);
    size_t tid = (size_t)bid * 256 + threadIdx.x;
    int node = (int)(tid >> 2);
    int q = (int)(tid & 3);                 // lane owns features 8q..8q+7
    float4 wv0 = ((const float4*)pw)[2*q];
    float4 wv1 = ((const float4*)pw)[2*q+1];
    float nn = wv0.x*wv0.x + wv0.y*wv0.y + wv0.z*wv0.z + wv0.w*wv0.w
             + wv1.x*wv1.x + wv1.y*wv1.y + wv1.z*wv1.z + wv1.w*wv1.w;
    nn += __shfl_xor(nn, 1); nn += __shfl_xor(nn, 2);
    float nrm = sqrtf(nn);
    bool valid = mask ? (mask[node] != 0) : true;
    float4 a0 = make_float4(0.f,0.f,0.f,0.f), a1 = make_float4(0.f,0.f,0.f,0.f);
    float4 b0 = make_float4(0.f,0.f,0.f,0.f), b1 = make_float4(0.f,0.f,0.f,0.f);
    if (valid) {
        uint4 su = *(const uint4*)(seedb + (size_t)node * 64 + q * 16);
        float2 s0 = unph2(su.x), s1 = unph2(su.y), s2 = unph2(su.z), s3 = unph2(su.w);
        a0 = make_float4(s0.x, s0.y, s1.x, s1.y);
        a1 = make_float4(s2.x, s2.y, s3.x, s3.y);
        #pragma unroll
        for (int p = 0; p < 2; ++p) {
            int2 m = meta[(size_t)p*NNODES + node];
            int e = m.x, end = m.x + m.y;
            for (; e + 1 < end; e += 2) {
                int2 ed0 = edge_sorted[e];
                int2 ed1 = edge_sorted[e+1];
                uint4 u0 = *(const uint4*)(yb + (size_t)ed0.x * 64 + q * 16);
                uint4 u1 = *(const uint4*)(yb + (size_t)ed1.x * 64 + q * 16);
                float w0 = __int_as_float(ed0.y);
                float w1 = __int_as_float(ed1.y);
                float2 p0, p1;
                p0 = unph2(u0.x); p1 = unph2(u0.y);
                a0.x = fmaf(p0.x, w0, a0.x); a0.y = fmaf(p0.y, w0, a0.y);
                a0.z = fmaf(p1.x, w0, a0.z); a0.w = fmaf(p1.y, w0, a0.w);
                p0 = unph2(u0.z); p1 = unph2(u0.w);
                a1.x = fmaf(p0.x, w0, a1.x); a1.y = fmaf(p0.y, w0, a1.y);
                a1.z = fmaf(p1.x, w0, a1.z); a1.w = fmaf(p1.y, w0, a1.w);
                p0 = unph2(u1.x); p1 = unph2(u1.y);
                b0.x = fmaf(p0.x, w1, b0.x); b0.y = fmaf(p0.y, w1, b0.y);
                b0.z = fmaf(p1.x, w1, b0.z); b0.w = fmaf(p1.y, w1, b0.w);
                p0 = unph2(u1.z); p1 = unph2(u1.w);
                b1.x = fmaf(p0.x, w1, b1.x); b1.y = fmaf(p0.y, w1, b1.y);
                b1.z = fmaf(p1.x, w1, b1.z); b1.w = fmaf(p1.y, w1, b1.w);
            }
            if (e < end) {
                int2 ed0 = edge_sorted[e];
                uint4 u0 = *(const uint4*)(yb + (size_t)ed0.x * 64 + q * 16);
                float w0 = __int_as_float(ed0.y);
                float2 p0, p1;
                p0 = unph2(u0.x); p1 = unph2(u0.y);
                a0.x = fmaf(p0.x, w0, a0.x); a0.y = fmaf(p0.y, w0, a0.y);
                a0.z = fmaf(p1.x, w0, a0.z); a0.w = fmaf(p1.y, w0, a0.w);
                p0 = unph2(u0.z); p1 = unph2(u0.w);
                a1.x = fmaf(p0.x, w0, a1.x); a1.y = fmaf(p0.y, w0, a1.y);
                a1.z = fmaf(p1.x, w0, a1.z); a1.w = fmaf(p1.y, w0, a1.w);
            }
        }
    }
    float hv0x = fmaxf(a0.x + b0.x, 0.f), hv0y = fmaxf(a0.y + b0.y, 0.f);
    float hv0z = fmaxf(a0.z + b0.z, 0.f), hv0w = fmaxf(a0.w + b0.w, 0.f);
    float hv1x = fmaxf(a1.x + b1.x, 0.f), hv1y = fmaxf(a1.y + b1.y, 0.f);
    float hv1z = fmaxf(a1.z + b1.z, 0.f), hv1w = fmaxf(a1.w + b1.w, 0.f);
    uint4 hw;
    hw.x = packh2(hv0x, hv0y);
    hw.y = packh2(hv0z, hv0w);
    hw.z = packh2(hv1x, hv1y);
    hw.w = packh2(hv1z, hv1w);
    *(uint4*)(hout + (size_t)node * 64 + q * 16) = hw;
    float dot = hv0x*wv0.x + hv0y*wv0.y + hv0z*wv0.z + hv0w*wv0.w
              + hv1x*wv1.x + hv1y*wv1.y + hv1z*wv1.z + hv1w*wv1.w;
    dot += __shfl_xor(dot, 1); dot += __shfl_xor(dot, 2);
    if (q == 0) s[node] = valid ? (dot / nrm) : -INFINITY;
}

// ---------- pooling: radix select with wave-level scans (few barriers) ----------
__global__ __launch_bounds__(1024) void k_pool(
    const float* __restrict__ s, const unsigned char* __restrict__ hb,
    float* __restrict__ ts_out, int* __restrict__ mask_out,
    float* __restrict__ xout, int ksel)
{
    __shared__ unsigned keys[NPG];
    __shared__ unsigned hist[256];
    __shared__ unsigned wpart[16];
    __shared__ unsigned char flag[NPG];
    __shared__ unsigned sh_bin, sh_krem;
    __shared__ float red[16*64];
    int t = threadIdx.x;
    int g = blockIdx.x;
    int lane = t & 63, wv = t >> 6;
    const float* sg = s + (size_t)g * NPG;
    for (int i = t; i < NPG; i += 1024) {
        unsigned u = __float_as_uint(sg[i]);
        keys[i] = (u & 0x80000000u) ? ~u : (u | 0x80000000u);
    }
    __syncthreads();
    unsigned prefix = 0u;
    unsigned krem = (unsigned)ksel;
    for (int level = 0; level < 4; ++level) {
        int shift = 24 - 8*level;
        if (t < 256) hist[t] = 0u;
        __syncthreads();
        unsigned pmask = level ? (0xFFFFFFFFu << (shift + 8)) : 0u;
        for (int i = t; i < NPG; i += 1024) {
            unsigned key = keys[i];
            if ((key & pmask) == prefix)
                atomicAdd(&hist[(key >> shift) & 0xFFu], 1u);
        }
        __syncthreads();
        unsigned vv = 0, sc = 0;
        if (t < 256) {
            vv = hist[255 - t];
            sc = wscan_u(vv, lane);
            if (lane == 63) wpart[wv] = sc;     // waves 0..3
        }
        __syncthreads();
        if (t < 256) {
            unsigned bsum = 0;
            for (int i = 0; i < wv; ++i) bsum += wpart[i];
            unsigned incl = bsum + sc;
            unsigned excl = incl - vv;
            if (incl >= krem && excl < krem) {
                sh_bin = (unsigned)(255 - t);
                sh_krem = krem - excl;
            }
        }
        __syncthreads();
        prefix |= (sh_bin << shift);
        krem = sh_krem;
    }
    __syncthreads();
    unsigned T = prefix;
    unsigned ties = krem;
    int base = t * 2;
    unsigned k0 = keys[base], k1 = keys[base+1];
    unsigned ceq = (k0 == T ? 1u : 0u) + (k1 == T ? 1u : 0u);
    unsigned sc2 = wscan_u(ceq, lane);
    if (lane == 63) wpart[wv] = sc2;            // waves 0..15
    __syncthreads();
    unsigned bsum2 = 0;
    for (int i = 0; i < wv; ++i) bsum2 += wpart[i];
    unsigned run = bsum2 + sc2 - ceq;
    {
        unsigned char f0, f1;
        if (k0 > T) f0 = 1;
        else if (k0 == T) { f0 = (run < ties) ? 1 : 0; run++; }
        else f0 = 0;
        if (k1 > T) f1 = 1;
        else if (k1 == T) { f1 = (run < ties) ? 1 : 0; run++; }
        else f1 = 0;
        flag[base] = f0; flag[base+1] = f1;
    }
    __syncthreads();

    float mx[32], sm[32];
    #pragma unroll
    for (int j=0;j<32;++j){ mx[j]=-INFINITY; sm[j]=0.f; }
    const unsigned char* hg = hb + (size_t)g * NPG * 64;
    for (int i = t; i < NPG; i += 1024) {
        bool sel = flag[i] != 0;
        float tsv = sel ? tanhf(sg[i]) : 0.f;
        const uint4* hr = (const uint4*)(hg + (size_t)i*64);
        #pragma unroll
        for (int c4=0;c4<4;++c4) {
            uint4 u = hr[c4];
            float2 p0=unph2(u.x), p1=unph2(u.y), p2=unph2(u.z), p3=unph2(u.w);
            float vals[8] = {p0.x,p0.y,p1.x,p1.y,p2.x,p2.y,p3.x,p3.y};
            #pragma unroll
            for (int j=0;j<8;++j) {
                float v = vals[j]*tsv;
                if (sel) { mx[c4*8+j]=fmaxf(mx[c4*8+j],v); sm[c4*8+j]+=v; }
            }
        }
        if (ts_out) ts_out[(size_t)g*NPG + i] = tsv;
        if (mask_out) mask_out[(size_t)g*NPG + i] = sel ? 1 : 0;
    }
    #pragma unroll
    for (int j=0;j<32;++j) {
        for (int off=32; off; off>>=1) {
            mx[j] = fmaxf(mx[j], __shfl_xor(mx[j], off));
            sm[j] += __shfl_xor(sm[j], off);
        }
    }
    if (lane == 0) {
        #pragma unroll
        for (int j=0;j<32;++j) { red[wv*64 + j] = mx[j]; red[wv*64 + 32 + j] = sm[j]; }
    }
    __syncthreads();
    if (t < 32) {
        float m = red[t], ss = red[32 + t];
        #pragma unroll
        for (int w=1; w<16; ++w) { m = fmaxf(m, red[w*64 + t]); ss += red[w*64 + 32 + t]; }
        xout[(size_t)g*64 + t] = m;
        xout[(size_t)g*64 + 32 + t] = ss / (float)ksel;
    }
}

__global__ __launch_bounds__(128) void k_readout(
    const float* __restrict__ x1, const float* __restrict__ x2,
    const float* __restrict__ l1W, const float* __restrict__ l1b,
    const float* __restrict__ l2W, const float* __restrict__ l2b,
    const float* __restrict__ l3W, const float* __restrict__ l3b,
    float* __restrict__ out)
{
    int g = threadIdx.x;
    float z[64];
    #pragma unroll
    for (int i=0;i<64;++i) z[i] = x1[g*64+i] + x2[g*64+i];
    float a1[32];
    for (int j=0;j<32;++j) {
        float acc = l1b[j];
        #pragma unroll
        for (int i=0;i<64;++i) acc = fmaf(z[i], l1W[i*32+j], acc);
        a1[j] = fmaxf(acc, 0.f);
    }
    float a2[16];
    for (int j=0;j<16;++j) {
        float acc = l2b[j];
        #pragma unroll
        for (int i=0;i<32;++i) acc = fmaf(a1[i], l2W[i*16+j], acc);
        a2[j] = fmaxf(acc, 0.f);
    }
    float o0 = l3b[0], o1 = l3b[1];
    #pragma unroll
    for (int i=0;i<16;++i) { o0 = fmaf(a2[i], l3W[i*2+0], o0); o1 = fmaf(a2[i], l3W[i*2+1], o1); }
    float m = fmaxf(o0, o1);
    float lse = m + logf(expf(o0-m) + expf(o1-m));
    out[g*2+0] = o0 - lse;
    out[g*2+1] = o1 - lse;
}

extern "C" void kernel_launch(void* const* d_in, const int* in_sizes, int n_in,
                              void* d_out, int out_size, void* d_ws, size_t ws_size,
                              hipStream_t stream)
{
    const float* x      = (const float*)d_in[0];
    const int*   ei     = (const int*)d_in[1];   // int32 (JAX x64 disabled)
    const float* eattr  = (const float*)d_in[2];
    const float* W1rel  = (const float*)d_in[4];
    const float* b1     = (const float*)d_in[5];
    const float* W1root = (const float*)d_in[6];
    const float* p1w    = (const float*)d_in[7];
    const float* W2rel  = (const float*)d_in[8];
    const float* b2     = (const float*)d_in[9];
    const float* W2root = (const float*)d_in[10];
    const float* p2w    = (const float*)d_in[11];
    const float* l1W    = (const float*)d_in[12];
    const float* l1b    = (const float*)d_in[13];
    const float* l2W    = (const float*)d_in[14];
    const float* l2b    = (const float*)d_in[15];
    const float* l3W    = (const float*)d_in[16];
    const float* l3b    = (const float*)d_in[17];
    const int* srcp = ei;
    const int* dstp = ei + NEDGES;

    unsigned char* yb    = (unsigned char*)d_ws;      // [NNODES,32] fp16 (16 MB)
    unsigned char* seedb = yb + (size_t)NNODES*64;    // [NNODES,32] fp16 (16 MB)
    unsigned char* hb    = seedb + (size_t)NNODES*64; // [NNODES,32] fp16 (16 MB)
    float* s1   = (float*)(hb + (size_t)NNODES*64);   // [NNODES]
    float* ts   = s1 + NNODES;                        // [NNODES]
    int*   mask = (int*)(ts + NNODES);                // [NNODES]
    float* x1   = (float*)(mask + NNODES);            // [128,64]
    float* x2   = x1 + NGRAPH*64;                     // [128,64]
    int2*  meta = (int2*)(x2 + NGRAPH*64);            // [2*NNODES] (start,count)
    int2*  edge_sorted = (int2*)(meta + 2*NNODES);    // [NEDGES] (src, ew)
    float* out  = (float*)d_out;

    dim3 b256(256);
    // ---- partitioned CSR: 2 WGs per graph (LDS build, deterministic) ----
    k_csr<<<NGRAPH*2, dim3(1024), 0, stream>>>(srcp, dstp, eattr, meta,
                                               edge_sorted);
    // ---- conv1 front-end + gather/score (XCD-swizzled, 4 lanes/node) ----
    k_gemm64<<<NNODES/128, b256, 0, stream>>>(x, W1rel, W1root, b1, yb, seedb);
    k_gather<<<NNODES*4/256, b256, 0, stream>>>(meta, edge_sorted,
                                                yb, p1w, nullptr, seedb, hb, s1);
    // ---- pool1 (ts + mask + x1) ----
    k_pool<<<NGRAPH, dim3(1024), 0, stream>>>(s1, hb, ts, mask, x1, KSEL1);
    // ---- conv2 front-end (ts fused) + gather/score ----
    k_gemm32<<<NNODES/128, b256, 0, stream>>>(hb, ts, W2rel, W2root, b2, yb, seedb);
    k_gather<<<NNODES*4/256, b256, 0, stream>>>(meta, edge_sorted,
                                                yb, p2w, mask, seedb, hb, s1);
    // ---- pool2 (x2 only) ----
    k_pool<<<NGRAPH, dim3(1024), 0, stream>>>(s1, hb, nullptr, nullptr, x2, KSEL2);
    // ---- readout MLP ----
    k_readout<<<1, 128, 0, stream>>>(x1, x2, l1W, l1b, l2W, l2b, l3W, l3b, out);
}

// Round 23
// 204.720 us; speedup vs baseline: 1.2063x; 1.0305x over previous
//
#include <hip/hip_runtime.h>
#include <hip/hip_fp16.h>
#include <math.h>

#define NNODES (128*2048)
#define NEDGES (NNODES*8)
#define NPG 2048
#define EPG (NPG*8)
#define HPG (EPG/2)          // 8192 edges per partition
#define NGRAPH 128
#define KSEL1 1639
#define KSEL2 1312

typedef _Float16 half2_t __attribute__((ext_vector_type(2)));

__device__ __forceinline__ unsigned packh2(float a, float b) {
    __half2 h = __floats2half2_rn(a, b);
    return *reinterpret_cast<unsigned*>(&h);
}
__device__ __forceinline__ float2 unph2(unsigned u) {
    __half2 h = *reinterpret_cast<__half2*>(&u);
    return __half22float2(h);
}
// fp16-pair dot with fp32 accumulate (v_dot2_f32_f16); exact fallback.
__device__ __forceinline__ float fdot2u(unsigned a, unsigned b, float c) {
#if __has_builtin(__builtin_amdgcn_fdot2)
    half2_t ha = *reinterpret_cast<half2_t*>(&a);
    half2_t hb = *reinterpret_cast<half2_t*>(&b);
    return __builtin_amdgcn_fdot2(ha, hb, c, false);
#else
    float2 fa = unph2(a), fb = unph2(b);
    return fmaf(fa.y, fb.y, fmaf(fa.x, fb.x, c));
#endif
}
__device__ __forceinline__ unsigned wscan_u(unsigned v, int lane) {
    #pragma unroll
    for (int off = 1; off < 64; off <<= 1) {
        unsigned n = __shfl_up(v, off);
        if (lane >= off) v += n;
    }
    return v;
}
__device__ __forceinline__ int wscan_i(int v, int lane) {
    #pragma unroll
    for (int off = 1; off < 64; off <<= 1) {
        int n = __shfl_up(v, off);
        if (lane >= off) v += n;
    }
    return v;
}

// ---------- partitioned CSR build, fully in LDS (deterministic) ----------
__global__ __launch_bounds__(1024) void k_csr(
    const int* __restrict__ src, const int* __restrict__ dst,
    const float* __restrict__ ew, int2* __restrict__ meta,
    int2* __restrict__ edge_sorted)
{
    __shared__ int2 ebuf[HPG];     // 64 KB
    __shared__ int cnt[NPG];       // 8 KB
    __shared__ int curs[NPG];      // 8 KB
    __shared__ int wpart[16];
    int t = threadIdx.x;
    int lane = t & 63, wv = t >> 6;
    int bid = blockIdx.x;
    int g = bid >> 1, part = bid & 1;
    const int ebase = g * EPG + part * HPG;
    int ds[8], ss[8]; float wws[8];
    #pragma unroll
    for (int j=0;j<8;++j) {
        int idx = ebase + t + 1024*j;
        ds[j] = dst[idx] & (NPG-1);
        ss[j] = src[idx];
        wws[j] = ew[idx];
    }
    for (int i = t; i < NPG; i += 1024) cnt[i] = 0;
    __syncthreads();
    #pragma unroll
    for (int j=0;j<8;++j) atomicAdd(&cnt[ds[j]], 1);
    __syncthreads();
    int base = t * 2;
    int l0 = cnt[base], l1 = cnt[base+1];
    int s0 = l0 + l1;
    int sc = wscan_i(s0, lane);
    if (lane == 63) wpart[wv] = sc;
    __syncthreads();
    int b = 0;
    for (int i = 0; i < wv; ++i) b += wpart[i];
    int run = b + sc - s0;
    curs[base] = run; curs[base+1] = run + l0;
    __syncthreads();
    for (int i = t; i < NPG; i += 1024)
        meta[(size_t)part*NNODES + g*NPG + i] = make_int2(ebase + curs[i], cnt[i]);
    __syncthreads();
    #pragma unroll
    for (int j=0;j<8;++j) {
        int pos = atomicAdd(&curs[ds[j]], 1);
        ebuf[pos] = make_int2(ss[j], __float_as_int(wws[j]));
    }
    __syncthreads();
    for (int i = t; i < NPG; i += 1024) {
        int cv = cnt[i];
        if (cv > 1) {
            int beg = curs[i] - cv;
            for (int a = 1; a < cv; ++a) {
                int2 key = ebuf[beg + a];
                unsigned long long kk =
                    ((unsigned long long)(unsigned)key.x << 32) | (unsigned)key.y;
                int p = beg + a - 1;
                while (p >= beg) {
                    int2 cur = ebuf[p];
                    unsigned long long ck =
                        ((unsigned long long)(unsigned)cur.x << 32) | (unsigned)cur.y;
                    if (ck <= kk) break;
                    ebuf[p + 1] = cur;
                    --p;
                }
                ebuf[p + 1] = key;
            }
        }
    }
    __syncthreads();
    #pragma unroll
    for (int j=0;j<8;++j) {
        int i = t + 1024*j;
        edge_sorted[ebase + i] = ebuf[i];
    }
}

// ---------- conv1 front-end: fp16-pair dot2, single staging pass ----------
// xh[128][34] packed fp16 pairs (k,k+1); wh[32 kpairs][64 outs] packed pairs.
// thread t: q=t>>5 (8 output groups of 8: q<4 -> y, q>=4 -> seed), ng=t&31
// owns rows ng+32i. LDS ~25.7 KB -> 6 WGs/CU.
#define XHP 34
__global__ __launch_bounds__(256, 4) void k_gemm64(
    const float* __restrict__ x, const float* __restrict__ Wrel,
    const float* __restrict__ Wroot, const float* __restrict__ b,
    unsigned char* __restrict__ yb, unsigned char* __restrict__ seedb)
{
    __shared__ unsigned xh[128*XHP];   // 17.4 KB
    __shared__ unsigned wh[32*64];     // 8 KB
    __shared__ float bb[32];
    int t = threadIdx.x;
    for (int i = t; i < 32*64; i += 256) {
        int kp = i >> 6, j = i & 63;
        float wa = (j < 32) ? Wrel[(2*kp)*32 + j]   : Wroot[(2*kp)*32 + (j-32)];
        float wb = (j < 32) ? Wrel[(2*kp+1)*32 + j] : Wroot[(2*kp+1)*32 + (j-32)];
        wh[i] = packh2(wa, wb);
    }
    if (t < 32) bb[t] = b[t];
    size_t nb = (size_t)blockIdx.x * 128;
    {
        const float4* xg4 = (const float4*)(x + nb*64);
        #pragma unroll
        for (int jj = 0; jj < 8; ++jj) {
            int i = t + 256*jj;
            int row = i >> 4, c = i & 15;
            float4 v = xg4[i];
            uint2 pk;
            pk.x = packh2(v.x, v.y);
            pk.y = packh2(v.z, v.w);
            *(uint2*)(&xh[row*XHP + c*2]) = pk;
        }
    }
    __syncthreads();
    int q = t >> 5, ng = t & 31;
    float acc[4][8];
    #pragma unroll
    for (int i=0;i<4;++i)
        #pragma unroll
        for (int j=0;j<8;++j) acc[i][j]=0.f;
    for (int kp = 0; kp < 32; kp += 2) {
        uint4 wA0 = *(const uint4*)(&wh[kp*64 + q*8]);
        uint4 wA1 = *(const uint4*)(&wh[kp*64 + q*8 + 4]);
        uint4 wB0 = *(const uint4*)(&wh[(kp+1)*64 + q*8]);
        uint4 wB1 = *(const uint4*)(&wh[(kp+1)*64 + q*8 + 4]);
        #pragma unroll
        for (int i=0;i<4;++i) {
            uint2 xv = *(const uint2*)(&xh[(ng + i*32)*XHP + kp]);
            acc[i][0]=fdot2u(xv.x, wA0.x, acc[i][0]);
            acc[i][1]=fdot2u(xv.x, wA0.y, acc[i][1]);
            acc[i][2]=fdot2u(xv.x, wA0.z, acc[i][2]);
            acc[i][3]=fdot2u(xv.x, wA0.w, acc[i][3]);
            acc[i][4]=fdot2u(xv.x, wA1.x, acc[i][4]);
            acc[i][5]=fdot2u(xv.x, wA1.y, acc[i][5]);
            acc[i][6]=fdot2u(xv.x, wA1.z, acc[i][6]);
            acc[i][7]=fdot2u(xv.x, wA1.w, acc[i][7]);
            acc[i][0]=fdot2u(xv.y, wB0.x, acc[i][0]);
            acc[i][1]=fdot2u(xv.y, wB0.y, acc[i][1]);
            acc[i][2]=fdot2u(xv.y, wB0.z, acc[i][2]);
            acc[i][3]=fdot2u(xv.y, wB0.w, acc[i][3]);
            acc[i][4]=fdot2u(xv.y, wB1.x, acc[i][4]);
            acc[i][5]=fdot2u(xv.y, wB1.y, acc[i][5]);
            acc[i][6]=fdot2u(xv.y, wB1.z, acc[i][6]);
            acc[i][7]=fdot2u(xv.y, wB1.w, acc[i][7]);
        }
    }
    if (q < 4) {               // y outputs (fp16), wave-uniform branch
        #pragma unroll
        for (int i=0;i<4;++i) {
            uint4 pk;
            pk.x = packh2(acc[i][0], acc[i][1]);
            pk.y = packh2(acc[i][2], acc[i][3]);
            pk.z = packh2(acc[i][4], acc[i][5]);
            pk.w = packh2(acc[i][6], acc[i][7]);
            *(uint4*)(yb + (nb + ng + i*32)*64 + q*16) = pk;
        }
    } else {
        int qq = q - 4;
        float b0=bb[qq*8+0],b1=bb[qq*8+1],b2=bb[qq*8+2],b3=bb[qq*8+3];
        float b4=bb[qq*8+4],b5=bb[qq*8+5],b6=bb[qq*8+6],b7=bb[qq*8+7];
        #pragma unroll
        for (int i=0;i<4;++i) {
            uint4 pk;
            pk.x = packh2(acc[i][0]+b0, acc[i][1]+b1);
            pk.y = packh2(acc[i][2]+b2, acc[i][3]+b3);
            pk.z = packh2(acc[i][4]+b4, acc[i][5]+b5);
            pk.w = packh2(acc[i][6]+b6, acc[i][7]+b7);
            *(uint4*)(seedb + (nb + ng + i*32)*64 + qq*16) = pk;
        }
    }
}

// ---------- conv2 front-end: h fp16 (already paired), dot2; ts folded ----------
// LDS ~21.5 KB -> 7 WGs/CU.
__global__ __launch_bounds__(256, 4) void k_gemm32(
    const unsigned char* __restrict__ hb, const float* __restrict__ ts,
    const float* __restrict__ Wrel, const float* __restrict__ Wroot,
    const float* __restrict__ b, unsigned char* __restrict__ yb,
    unsigned char* __restrict__ seedb)
{
    __shared__ unsigned xh[128*XHP];   // 17.4 KB
    __shared__ unsigned wh[16*64];     // 4 KB
    __shared__ float bb[32];
    int t = threadIdx.x;
    for (int i = t; i < 16*64; i += 256) {
        int kp = i >> 6, j = i & 63;
        float wa = (j < 32) ? Wrel[(2*kp)*32 + j]   : Wroot[(2*kp)*32 + (j-32)];
        float wb = (j < 32) ? Wrel[(2*kp+1)*32 + j] : Wroot[(2*kp+1)*32 + (j-32)];
        wh[i] = packh2(wa, wb);
    }
    if (t < 32) bb[t] = b[t];
    size_t nb = (size_t)blockIdx.x * 128;
    const unsigned char* hg = hb + nb * 64;
    #pragma unroll
    for (int jj = 0; jj < 4; ++jj) {
        int i = t + 256*jj;
        int row = i >> 3, c = i & 7;
        uint4 u = *(const uint4*)(hg + row*64 + c*16);
        uint2 lo; lo.x = u.x; lo.y = u.y;
        uint2 hi; hi.x = u.z; hi.y = u.w;
        *(uint2*)(&xh[row*XHP + c*4])     = lo;
        *(uint2*)(&xh[row*XHP + c*4 + 2]) = hi;
    }
    __syncthreads();
    int q = t >> 5, ng = t & 31;
    float tsv[4];
    #pragma unroll
    for (int i=0;i<4;++i) tsv[i] = ts[nb + ng + i*32];
    float acc[4][8];
    #pragma unroll
    for (int i=0;i<4;++i)
        #pragma unroll
        for (int j=0;j<8;++j) acc[i][j]=0.f;
    for (int kp = 0; kp < 16; kp += 2) {
        uint4 wA0 = *(const uint4*)(&wh[kp*64 + q*8]);
        uint4 wA1 = *(const uint4*)(&wh[kp*64 + q*8 + 4]);
        uint4 wB0 = *(const uint4*)(&wh[(kp+1)*64 + q*8]);
        uint4 wB1 = *(const uint4*)(&wh[(kp+1)*64 + q*8 + 4]);
        #pragma unroll
        for (int i=0;i<4;++i) {
            uint2 xv = *(const uint2*)(&xh[(ng + i*32)*XHP + kp]);
            acc[i][0]=fdot2u(xv.x, wA0.x, acc[i][0]);
            acc[i][1]=fdot2u(xv.x, wA0.y, acc[i][1]);
            acc[i][2]=fdot2u(xv.x, wA0.z, acc[i][2]);
            acc[i][3]=fdot2u(xv.x, wA0.w, acc[i][3]);
            acc[i][4]=fdot2u(xv.x, wA1.x, acc[i][4]);
            acc[i][5]=fdot2u(xv.x, wA1.y, acc[i][5]);
            acc[i][6]=fdot2u(xv.x, wA1.z, acc[i][6]);
            acc[i][7]=fdot2u(xv.x, wA1.w, acc[i][7]);
            acc[i][0]=fdot2u(xv.y, wB0.x, acc[i][0]);
            acc[i][1]=fdot2u(xv.y, wB0.y, acc[i][1]);
            acc[i][2]=fdot2u(xv.y, wB0.z, acc[i][2]);
            acc[i][3]=fdot2u(xv.y, wB0.w, acc[i][3]);
            acc[i][4]=fdot2u(xv.y, wB1.x, acc[i][4]);
            acc[i][5]=fdot2u(xv.y, wB1.y, acc[i][5]);
            acc[i][6]=fdot2u(xv.y, wB1.z, acc[i][6]);
            acc[i][7]=fdot2u(xv.y, wB1.w, acc[i][7]);
        }
    }
    if (q < 4) {
        #pragma unroll
        for (int i=0;i<4;++i) {
            float sc = tsv[i];
            uint4 pk;
            pk.x = packh2(acc[i][0]*sc, acc[i][1]*sc);
            pk.y = packh2(acc[i][2]*sc, acc[i][3]*sc);
            pk.z = packh2(acc[i][4]*sc, acc[i][5]*sc);
            pk.w = packh2(acc[i][6]*sc, acc[i][7]*sc);
            *(uint4*)(yb + (nb + ng + i*32)*64 + q*16) = pk;
        }
    } else {
        int qq = q - 4;
        float b0=bb[qq*8+0],b1=bb[qq*8+1],b2=bb[qq*8+2],b3=bb[qq*8+3];
        float b4=bb[qq*8+4],b5=bb[qq*8+5],b6=bb[qq*8+6],b7=bb[qq*8+7];
        #pragma unroll
        for (int i=0;i<4;++i) {
            float sc = tsv[i];
            uint4 pk;
            pk.x = packh2(acc[i][0]*sc+b0, acc[i][1]*sc+b1);
            pk.y = packh2(acc[i][2]*sc+b2, acc[i][3]*sc+b3);
            pk.z = packh2(acc[i][4]*sc+b4, acc[i][5]*sc+b5);
            pk.w = packh2(acc[i][6]*sc+b6, acc[i][7]*sc+b7);
            *(uint4*)(seedb + (nb + ng + i*32)*64 + qq*16) = pk;
        }
    }
}

// ---------- fused gather + relu + score ----------
__global__ __launch_bounds__(256) void k_gather(
    const int2* __restrict__ meta, const int2* __restrict__ edge_sorted,
    const unsigned char* __restrict__ yb, const float* __restrict__ pw,
    const int* __restrict__ mask, const unsigned char* __restrict__ seedb,
    unsigned char* __restrict__ hout, float* __restrict__ s)
{
    unsigned orig = blockIdx.x;
    unsigned nwg8 = gridDim.x >> 3;
    unsigned bid = (orig & 7u) * nwg8 + (orig >> 3);
    size_t tid = (size_t)bid * 256 + threadIdx.x;
    int node = (int)(tid >> 2);
    int q = (int)(tid & 3);                 // lane owns features 8q..8q+7
    float4 wv0 = ((const float4*)pw)[2*q];
    float4 wv1 = ((const float4*)pw)[2*q+1];
    float nn = wv0.x*wv0.x + wv0.y*wv0.y + wv0.z*wv0.z + wv0.w*wv0.w
             + wv1.x*wv1.x + wv1.y*wv1.y + wv1.z*wv1.z + wv1.w*wv1.w;
    nn += __shfl_xor(nn, 1); nn += __shfl_xor(nn, 2);
    float nrm = sqrtf(nn);
    bool valid = mask ? (mask[node] != 0) : true;
    float4 a0 = make_float4(0.f,0.f,0.f,0.f), a1 = make_float4(0.f,0.f,0.f,0.f);
    float4 b0 = make_float4(0.f,0.f,0.f,0.f), b1 = make_float4(0.f,0.f,0.f,0.f);
    if (valid) {
        uint4 su = *(const uint4*)(seedb + (size_t)node * 64 + q * 16);
        float2 s0 = unph2(su.x), s1 = unph2(su.y), s2 = unph2(su.z), s3 = unph2(su.w);
        a0 = make_float4(s0.x, s0.y, s1.x, s1.y);
        a1 = make_float4(s2.x, s2.y, s3.x, s3.y);
        #pragma unroll
        for (int p = 0; p < 2; ++p) {
            int2 m = meta[(size_t)p*NNODES + node];
            int e = m.x, end = m.x + m.y;
            for (; e + 1 < end; e += 2) {
                int2 ed0 = edge_sorted[e];
                int2 ed1 = edge_sorted[e+1];
                uint4 u0 = *(const uint4*)(yb + (size_t)ed0.x * 64 + q * 16);
                uint4 u1 = *(const uint4*)(yb + (size_t)ed1.x * 64 + q * 16);
                float w0 = __int_as_float(ed0.y);
                float w1 = __int_as_float(ed1.y);
                float2 p0, p1;
                p0 = unph2(u0.x); p1 = unph2(u0.y);
                a0.x = fmaf(p0.x, w0, a0.x); a0.y = fmaf(p0.y, w0, a0.y);
                a0.z = fmaf(p1.x, w0, a0.z); a0.w = fmaf(p1.y, w0, a0.w);
                p0 = unph2(u0.z); p1 = unph2(u0.w);
                a1.x = fmaf(p0.x, w0, a1.x); a1.y = fmaf(p0.y, w0, a1.y);
                a1.z = fmaf(p1.x, w0, a1.z); a1.w = fmaf(p1.y, w0, a1.w);
                p0 = unph2(u1.x); p1 = unph2(u1.y);
                b0.x = fmaf(p0.x, w1, b0.x); b0.y = fmaf(p0.y, w1, b0.y);
                b0.z = fmaf(p1.x, w1, b0.z); b0.w = fmaf(p1.y, w1, b0.w);
                p0 = unph2(u1.z); p1 = unph2(u1.w);
                b1.x = fmaf(p0.x, w1, b1.x); b1.y = fmaf(p0.y, w1, b1.y);
                b1.z = fmaf(p1.x, w1, b1.z); b1.w = fmaf(p1.y, w1, b1.w);
            }
            if (e < end) {
                int2 ed0 = edge_sorted[e];
                uint4 u0 = *(const uint4*)(yb + (size_t)ed0.x * 64 + q * 16);
                float w0 = __int_as_float(ed0.y);
                float2 p0, p1;
                p0 = unph2(u0.x); p1 = unph2(u0.y);
                a0.x = fmaf(p0.x, w0, a0.x); a0.y = fmaf(p0.y, w0, a0.y);
                a0.z = fmaf(p1.x, w0, a0.z); a0.w = fmaf(p1.y, w0, a0.w);
                p0 = unph2(u0.z); p1 = unph2(u0.w);
                a1.x = fmaf(p0.x, w0, a1.x); a1.y = fmaf(p0.y, w0, a1.y);
                a1.z = fmaf(p1.x, w0, a1.z); a1.w = fmaf(p1.y, w0, a1.w);
            }
        }
    }
    float hv0x = fmaxf(a0.x + b0.x, 0.f), hv0y = fmaxf(a0.y + b0.y, 0.f);
    float hv0z = fmaxf(a0.z + b0.z, 0.f), hv0w = fmaxf(a0.w + b0.w, 0.f);
    float hv1x = fmaxf(a1.x + b1.x, 0.f), hv1y = fmaxf(a1.y + b1.y, 0.f);
    float hv1z = fmaxf(a1.z + b1.z, 0.f), hv1w = fmaxf(a1.w + b1.w, 0.f);
    uint4 hw;
    hw.x = packh2(hv0x, hv0y);
    hw.y = packh2(hv0z, hv0w);
    hw.z = packh2(hv1x, hv1y);
    hw.w = packh2(hv1z, hv1w);
    *(uint4*)(hout + (size_t)node * 64 + q * 16) = hw;
    float dot = hv0x*wv0.x + hv0y*wv0.y + hv0z*wv0.z + hv0w*wv0.w
              + hv1x*wv1.x + hv1y*wv1.y + hv1z*wv1.z + hv1w*wv1.w;
    dot += __shfl_xor(dot, 1); dot += __shfl_xor(dot, 2);
    if (q == 0) s[node] = valid ? (dot / nrm) : -INFINITY;
}

// ---------- pooling: radix select with wave-level scans ----------
__global__ __launch_bounds__(1024) void k_pool(
    const float* __restrict__ s, const unsigned char* __restrict__ hb,
    float* __restrict__ ts_out, int* __restrict__ mask_out,
    float* __restrict__ xout, int ksel)
{
    __shared__ unsigned keys[NPG];
    __shared__ unsigned hist[256];
    __shared__ unsigned wpart[16];
    __shared__ unsigned char flag[NPG];
    __shared__ unsigned sh_bin, sh_krem;
    __shared__ float red[16*64];
    int t = threadIdx.x;
    int g = blockIdx.x;
    int lane = t & 63, wv = t >> 6;
    const float* sg = s + (size_t)g * NPG;
    for (int i = t; i < NPG; i += 1024) {
        unsigned u = __float_as_uint(sg[i]);
        keys[i] = (u & 0x80000000u) ? ~u : (u | 0x80000000u);
    }
    __syncthreads();
    unsigned prefix = 0u;
    unsigned krem = (unsigned)ksel;
    for (int level = 0; level < 4; ++level) {
        int shift = 24 - 8*level;
        if (t < 256) hist[t] = 0u;
        __syncthreads();
        unsigned pmask = level ? (0xFFFFFFFFu << (shift + 8)) : 0u;
        for (int i = t; i < NPG; i += 1024) {
            unsigned key = keys[i];
            if ((key & pmask) == prefix)
                atomicAdd(&hist[(key >> shift) & 0xFFu], 1u);
        }
        __syncthreads();
        unsigned vv = 0, sc = 0;
        if (t < 256) {
            vv = hist[255 - t];
            sc = wscan_u(vv, lane);
            if (lane == 63) wpart[wv] = sc;
        }
        __syncthreads();
        if (t < 256) {
            unsigned bsum = 0;
            for (int i = 0; i < wv; ++i) bsum += wpart[i];
            unsigned incl = bsum + sc;
            unsigned excl = incl - vv;
            if (incl >= krem && excl < krem) {
                sh_bin = (unsigned)(255 - t);
                sh_krem = krem - excl;
            }
        }
        __syncthreads();
        prefix |= (sh_bin << shift);
        krem = sh_krem;
    }
    __syncthreads();
    unsigned T = prefix;
    unsigned ties = krem;
    int base = t * 2;
    unsigned k0 = keys[base], k1 = keys[base+1];
    unsigned ceq = (k0 == T ? 1u : 0u) + (k1 == T ? 1u : 0u);
    unsigned sc2 = wscan_u(ceq, lane);
    if (lane == 63) wpart[wv] = sc2;
    __syncthreads();
    unsigned bsum2 = 0;
    for (int i = 0; i < wv; ++i) bsum2 += wpart[i];
    unsigned run = bsum2 + sc2 - ceq;
    {
        unsigned char f0, f1;
        if (k0 > T) f0 = 1;
        else if (k0 == T) { f0 = (run < ties) ? 1 : 0; run++; }
        else f0 = 0;
        if (k1 > T) f1 = 1;
        else if (k1 == T) { f1 = (run < ties) ? 1 : 0; run++; }
        else f1 = 0;
        flag[base] = f0; flag[base+1] = f1;
    }
    __syncthreads();

    float mx[32], sm[32];
    #pragma unroll
    for (int j=0;j<32;++j){ mx[j]=-INFINITY; sm[j]=0.f; }
    const unsigned char* hg = hb + (size_t)g * NPG * 64;
    for (int i = t; i < NPG; i += 1024) {
        bool sel = flag[i] != 0;
        float tsv = sel ? tanhf(sg[i]) : 0.f;
        const uint4* hr = (const uint4*)(hg + (size_t)i*64);
        #pragma unroll
        for (int c4=0;c4<4;++c4) {
            uint4 u = hr[c4];
            float2 p0=unph2(u.x), p1=unph2(u.y), p2=unph2(u.z), p3=unph2(u.w);
            float vals[8] = {p0.x,p0.y,p1.x,p1.y,p2.x,p2.y,p3.x,p3.y};
            #pragma unroll
            for (int j=0;j<8;++j) {
                float v = vals[j]*tsv;
                if (sel) { mx[c4*8+j]=fmaxf(mx[c4*8+j],v); sm[c4*8+j]+=v; }
            }
        }
        if (ts_out) ts_out[(size_t)g*NPG + i] = tsv;
        if (mask_out) mask_out[(size_t)g*NPG + i] = sel ? 1 : 0;
    }
    #pragma unroll
    for (int j=0;j<32;++j) {
        for (int off=32; off; off>>=1) {
            mx[j] = fmaxf(mx[j], __shfl_xor(mx[j], off));
            sm[j] += __shfl_xor(sm[j], off);
        }
    }
    if (lane == 0) {
        #pragma unroll
        for (int j=0;j<32;++j) { red[wv*64 + j] = mx[j]; red[wv*64 + 32 + j] = sm[j]; }
    }
    __syncthreads();
    if (t < 32) {
        float m = red[t], ss = red[32 + t];
        #pragma unroll
        for (int w=1; w<16; ++w) { m = fmaxf(m, red[w*64 + t]); ss += red[w*64 + 32 + t]; }
        xout[(size_t)g*64 + t] = m;
        xout[(size_t)g*64 + 32 + t] = ss / (float)ksel;
    }
}

__global__ __launch_bounds__(128) void k_readout(
    const float* __restrict__ x1, const float* __restrict__ x2,
    const float* __restrict__ l1W, const float* __restrict__ l1b,
    const float* __restrict__ l2W, const float* __restrict__ l2b,
    const float* __restrict__ l3W, const float* __restrict__ l3b,
    float* __restrict__ out)
{
    int g = threadIdx.x;
    float z[64];
    #pragma unroll
    for (int i=0;i<64;++i) z[i] = x1[g*64+i] + x2[g*64+i];
    float a1[32];
    for (int j=0;j<32;++j) {
        float acc = l1b[j];
        #pragma unroll
        for (int i=0;i<64;++i) acc = fmaf(z[i], l1W[i*32+j], acc);
        a1[j] = fmaxf(acc, 0.f);
    }
    float a2[16];
    for (int j=0;j<16;++j) {
        float acc = l2b[j];
        #pragma unroll
        for (int i=0;i<32;++i) acc = fmaf(a1[i], l2W[i*16+j], acc);
        a2[j] = fmaxf(acc, 0.f);
    }
    float o0 = l3b[0], o1 = l3b[1];
    #pragma unroll
    for (int i=0;i<16;++i) { o0 = fmaf(a2[i], l3W[i*2+0], o0); o1 = fmaf(a2[i], l3W[i*2+1], o1); }
    float m = fmaxf(o0, o1);
    float lse = m + logf(expf(o0-m) + expf(o1-m));
    out[g*2+0] = o0 - lse;
    out[g*2+1] = o1 - lse;
}

extern "C" void kernel_launch(void* const* d_in, const int* in_sizes, int n_in,
                              void* d_out, int out_size, void* d_ws, size_t ws_size,
                              hipStream_t stream)
{
    const float* x      = (const float*)d_in[0];
    const int*   ei     = (const int*)d_in[1];   // int32 (JAX x64 disabled)
    const float* eattr  = (const float*)d_in[2];
    const float* W1rel  = (const float*)d_in[4];
    const float* b1     = (const float*)d_in[5];
    const float* W1root = (const float*)d_in[6];
    const float* p1w    = (const float*)d_in[7];
    const float* W2rel  = (const float*)d_in[8];
    const float* b2     = (const float*)d_in[9];
    const float* W2root = (const float*)d_in[10];
    const float* p2w    = (const float*)d_in[11];
    const float* l1W    = (const float*)d_in[12];
    const float* l1b    = (const float*)d_in[13];
    const float* l2W    = (const float*)d_in[14];
    const float* l2b    = (const float*)d_in[15];
    const float* l3W    = (const float*)d_in[16];
    const float* l3b    = (const float*)d_in[17];
    const int* srcp = ei;
    const int* dstp = ei + NEDGES;

    unsigned char* yb    = (unsigned char*)d_ws;      // [NNODES,32] fp16 (16 MB)
    unsigned char* seedb = yb + (size_t)NNODES*64;    // [NNODES,32] fp16 (16 MB)
    unsigned char* hb    = seedb + (size_t)NNODES*64; // [NNODES,32] fp16 (16 MB)
    float* s1   = (float*)(hb + (size_t)NNODES*64);   // [NNODES]
    float* ts   = s1 + NNODES;                        // [NNODES]
    int*   mask = (int*)(ts + NNODES);                // [NNODES]
    float* x1   = (float*)(mask + NNODES);            // [128,64]
    float* x2   = x1 + NGRAPH*64;                     // [128,64]
    int2*  meta = (int2*)(x2 + NGRAPH*64);            // [2*NNODES] (start,count)
    int2*  edge_sorted = (int2*)(meta + 2*NNODES);    // [NEDGES] (src, ew)
    float* out  = (float*)d_out;

    dim3 b256(256);
    // ---- partitioned CSR: 2 WGs per graph (LDS build, deterministic) ----
    k_csr<<<NGRAPH*2, dim3(1024), 0, stream>>>(srcp, dstp, eattr, meta,
                                               edge_sorted);
    // ---- conv1 front-end (dot2) + gather/score ----
    k_gemm64<<<NNODES/128, b256, 0, stream>>>(x, W1rel, W1root, b1, yb, seedb);
    k_gather<<<NNODES*4/256, b256, 0, stream>>>(meta, edge_sorted,
                                                yb, p1w, nullptr, seedb, hb, s1);
    // ---- pool1 (ts + mask + x1) ----
    k_pool<<<NGRAPH, dim3(1024), 0, stream>>>(s1, hb, ts, mask, x1, KSEL1);
    // ---- conv2 front-end (dot2, ts fused) + gather/score ----
    k_gemm32<<<NNODES/128, b256, 0, stream>>>(hb, ts, W2rel, W2root, b2, yb, seedb);
    k_gather<<<NNODES*4/256, b256, 0, stream>>>(meta, edge_sorted,
                                                yb, p2w, mask, seedb, hb, s1);
    // ---- pool2 (x2 only) ----
    k_pool<<<NGRAPH, dim3(1024), 0, stream>>>(s1, hb, nullptr, nullptr, x2, KSEL2);
    // ---- readout MLP ----
    k_readout<<<1, 128, 0, stream>>>(x1, x2, l1W, l1b, l2W, l2b, l3W, l3b, out);
}

// Round 24
// 188.211 us; speedup vs baseline: 1.3121x; 1.0877x over previous
//
#include <hip/hip_runtime.h>
#include <hip/hip_fp16.h>
#include <math.h>

#define NNODES (128*2048)
#define NEDGES (NNODES*8)
#define NPG 2048
#define EPG (NPG*8)
#define HPG (EPG/2)          // 8192 edges per partition
#define NGRAPH 128
#define KSEL1 1639
#define KSEL2 1312

typedef _Float16 half2_t __attribute__((ext_vector_type(2)));

__device__ __forceinline__ unsigned packh2(float a, float b) {
    __half2 h = __floats2half2_rn(a, b);
    return *reinterpret_cast<unsigned*>(&h);
}
__device__ __forceinline__ float2 unph2(unsigned u) {
    __half2 h = *reinterpret_cast<__half2*>(&u);
    return __half22float2(h);
}
// fp16-pair dot with fp32 accumulate (v_dot2_f32_f16); exact fallback.
__device__ __forceinline__ float fdot2u(unsigned a, unsigned b, float c) {
#if __has_builtin(__builtin_amdgcn_fdot2)
    half2_t ha = *reinterpret_cast<half2_t*>(&a);
    half2_t hb = *reinterpret_cast<half2_t*>(&b);
    return __builtin_amdgcn_fdot2(ha, hb, c, false);
#else
    float2 fa = unph2(a), fb = unph2(b);
    return fmaf(fa.y, fb.y, fmaf(fa.x, fb.x, c));
#endif
}
__device__ __forceinline__ unsigned wscan_u(unsigned v, int lane) {
    #pragma unroll
    for (int off = 1; off < 64; off <<= 1) {
        unsigned n = __shfl_up(v, off);
        if (lane >= off) v += n;
    }
    return v;
}
__device__ __forceinline__ int wscan_i(int v, int lane) {
    #pragma unroll
    for (int off = 1; off < 64; off <<= 1) {
        int n = __shfl_up(v, off);
        if (lane >= off) v += n;
    }
    return v;
}

// ---------- partitioned CSR build, fully in LDS (deterministic) ----------
// Packed u16 histogram halves LDS (76.1 KB total) -> 2 WGs/CU.
__global__ __launch_bounds__(1024) void k_csr(
    const int* __restrict__ src, const int* __restrict__ dst,
    const float* __restrict__ ew, int2* __restrict__ meta,
    int2* __restrict__ edge_sorted)
{
    __shared__ int2 ebuf[HPG];     // 64 KB
    __shared__ int cntp[NPG/2];    // 4 KB (two u16 counts per int)
    __shared__ int curs[NPG];      // 8 KB
    __shared__ int wpart[16];
    int t = threadIdx.x;
    int lane = t & 63, wv = t >> 6;
    int bid = blockIdx.x;
    int g = bid >> 1, part = bid & 1;
    const int ebase = g * EPG + part * HPG;
    int ds[8], ss[8]; float wws[8];
    #pragma unroll
    for (int j=0;j<8;++j) {
        int idx = ebase + t + 1024*j;
        ds[j] = dst[idx] & (NPG-1);
        ss[j] = src[idx];
        wws[j] = ew[idx];
    }
    for (int i = t; i < NPG/2; i += 1024) cntp[i] = 0;
    __syncthreads();
    #pragma unroll
    for (int j=0;j<8;++j)
        atomicAdd(&cntp[ds[j] >> 1], 1 << ((ds[j] & 1) * 16));
    __syncthreads();
    int base = t * 2;
    int pc = cntp[t];
    int l0 = pc & 0xFFFF, l1 = (pc >> 16) & 0xFFFF;
    int s0 = l0 + l1;
    int sc = wscan_i(s0, lane);
    if (lane == 63) wpart[wv] = sc;
    __syncthreads();
    int b = 0;
    for (int i = 0; i < wv; ++i) b += wpart[i];
    int run = b + sc - s0;
    curs[base] = run; curs[base+1] = run + l0;
    __syncthreads();
    for (int i = t; i < NPG; i += 1024) {
        int cv = (cntp[i >> 1] >> ((i & 1) * 16)) & 0xFFFF;
        meta[(size_t)part*NNODES + g*NPG + i] = make_int2(ebase + curs[i], cv);
    }
    __syncthreads();
    #pragma unroll
    for (int j=0;j<8;++j) {
        int pos = atomicAdd(&curs[ds[j]], 1);
        ebuf[pos] = make_int2(ss[j], __float_as_int(wws[j]));
    }
    __syncthreads();
    // canonical per-bucket order (insertion sort in LDS)
    for (int i = t; i < NPG; i += 1024) {
        int cv = (cntp[i >> 1] >> ((i & 1) * 16)) & 0xFFFF;
        if (cv > 1) {
            int beg = curs[i] - cv;              // curs[i] is now start+cnt
            for (int a = 1; a < cv; ++a) {
                int2 key = ebuf[beg + a];
                unsigned long long kk =
                    ((unsigned long long)(unsigned)key.x << 32) | (unsigned)key.y;
                int p = beg + a - 1;
                while (p >= beg) {
                    int2 cur = ebuf[p];
                    unsigned long long ck =
                        ((unsigned long long)(unsigned)cur.x << 32) | (unsigned)cur.y;
                    if (ck <= kk) break;
                    ebuf[p + 1] = cur;
                    --p;
                }
                ebuf[p + 1] = key;
            }
        }
    }
    __syncthreads();
    #pragma unroll
    for (int j=0;j<8;++j) {
        int i = t + 1024*j;
        edge_sorted[ebase + i] = ebuf[i];
    }
}

// ---------- conv1 front-end: fp16-pair dot2, single staging pass ----------
#define XHP 34
__global__ __launch_bounds__(256, 4) void k_gemm64(
    const float* __restrict__ x, const float* __restrict__ Wrel,
    const float* __restrict__ Wroot, const float* __restrict__ b,
    unsigned char* __restrict__ yb, unsigned char* __restrict__ seedb)
{
    __shared__ unsigned xh[128*XHP];   // 17.4 KB
    __shared__ unsigned wh[32*64];     // 8 KB
    __shared__ float bb[32];
    int t = threadIdx.x;
    for (int i = t; i < 32*64; i += 256) {
        int kp = i >> 6, j = i & 63;
        float wa = (j < 32) ? Wrel[(2*kp)*32 + j]   : Wroot[(2*kp)*32 + (j-32)];
        float wb = (j < 32) ? Wrel[(2*kp+1)*32 + j] : Wroot[(2*kp+1)*32 + (j-32)];
        wh[i] = packh2(wa, wb);
    }
    if (t < 32) bb[t] = b[t];
    size_t nb = (size_t)blockIdx.x * 128;
    {
        const float4* xg4 = (const float4*)(x + nb*64);
        #pragma unroll
        for (int jj = 0; jj < 8; ++jj) {
            int i = t + 256*jj;
            int row = i >> 4, c = i & 15;
            float4 v = xg4[i];
            uint2 pk;
            pk.x = packh2(v.x, v.y);
            pk.y = packh2(v.z, v.w);
            *(uint2*)(&xh[row*XHP + c*2]) = pk;
        }
    }
    __syncthreads();
    int q = t >> 5, ng = t & 31;
    float acc[4][8];
    #pragma unroll
    for (int i=0;i<4;++i)
        #pragma unroll
        for (int j=0;j<8;++j) acc[i][j]=0.f;
    for (int kp = 0; kp < 32; kp += 2) {
        uint4 wA0 = *(const uint4*)(&wh[kp*64 + q*8]);
        uint4 wA1 = *(const uint4*)(&wh[kp*64 + q*8 + 4]);
        uint4 wB0 = *(const uint4*)(&wh[(kp+1)*64 + q*8]);
        uint4 wB1 = *(const uint4*)(&wh[(kp+1)*64 + q*8 + 4]);
        #pragma unroll
        for (int i=0;i<4;++i) {
            uint2 xv = *(const uint2*)(&xh[(ng + i*32)*XHP + kp]);
            acc[i][0]=fdot2u(xv.x, wA0.x, acc[i][0]);
            acc[i][1]=fdot2u(xv.x, wA0.y, acc[i][1]);
            acc[i][2]=fdot2u(xv.x, wA0.z, acc[i][2]);
            acc[i][3]=fdot2u(xv.x, wA0.w, acc[i][3]);
            acc[i][4]=fdot2u(xv.x, wA1.x, acc[i][4]);
            acc[i][5]=fdot2u(xv.x, wA1.y, acc[i][5]);
            acc[i][6]=fdot2u(xv.x, wA1.z, acc[i][6]);
            acc[i][7]=fdot2u(xv.x, wA1.w, acc[i][7]);
            acc[i][0]=fdot2u(xv.y, wB0.x, acc[i][0]);
            acc[i][1]=fdot2u(xv.y, wB0.y, acc[i][1]);
            acc[i][2]=fdot2u(xv.y, wB0.z, acc[i][2]);
            acc[i][3]=fdot2u(xv.y, wB0.w, acc[i][3]);
            acc[i][4]=fdot2u(xv.y, wB1.x, acc[i][4]);
            acc[i][5]=fdot2u(xv.y, wB1.y, acc[i][5]);
            acc[i][6]=fdot2u(xv.y, wB1.z, acc[i][6]);
            acc[i][7]=fdot2u(xv.y, wB1.w, acc[i][7]);
        }
    }
    if (q < 4) {               // y outputs (fp16), wave-uniform branch
        #pragma unroll
        for (int i=0;i<4;++i) {
            uint4 pk;
            pk.x = packh2(acc[i][0], acc[i][1]);
            pk.y = packh2(acc[i][2], acc[i][3]);
            pk.z = packh2(acc[i][4], acc[i][5]);
            pk.w = packh2(acc[i][6], acc[i][7]);
            *(uint4*)(yb + (nb + ng + i*32)*64 + q*16) = pk;
        }
    } else {
        int qq = q - 4;
        float b0=bb[qq*8+0],b1=bb[qq*8+1],b2=bb[qq*8+2],b3=bb[qq*8+3];
        float b4=bb[qq*8+4],b5=bb[qq*8+5],b6=bb[qq*8+6],b7=bb[qq*8+7];
        #pragma unroll
        for (int i=0;i<4;++i) {
            uint4 pk;
            pk.x = packh2(acc[i][0]+b0, acc[i][1]+b1);
            pk.y = packh2(acc[i][2]+b2, acc[i][3]+b3);
            pk.z = packh2(acc[i][4]+b4, acc[i][5]+b5);
            pk.w = packh2(acc[i][6]+b6, acc[i][7]+b7);
            *(uint4*)(seedb + (nb + ng + i*32)*64 + qq*16) = pk;
        }
    }
}

// ---------- conv2 front-end: h fp16 (already paired), dot2; ts folded ----------
__global__ __launch_bounds__(256, 4) void k_gemm32(
    const unsigned char* __restrict__ hb, const float* __restrict__ ts,
    const float* __restrict__ Wrel, const float* __restrict__ Wroot,
    const float* __restrict__ b, unsigned char* __restrict__ yb,
    unsigned char* __restrict__ seedb)
{
    __shared__ unsigned xh[128*XHP];   // 17.4 KB
    __shared__ unsigned wh[16*64];     // 4 KB
    __shared__ float bb[32];
    int t = threadIdx.x;
    for (int i = t; i < 16*64; i += 256) {
        int kp = i >> 6, j = i & 63;
        float wa = (j < 32) ? Wrel[(2*kp)*32 + j]   : Wroot[(2*kp)*32 + (j-32)];
        float wb = (j < 32) ? Wrel[(2*kp+1)*32 + j] : Wroot[(2*kp+1)*32 + (j-32)];
        wh[i] = packh2(wa, wb);
    }
    if (t < 32) bb[t] = b[t];
    size_t nb = (size_t)blockIdx.x * 128;
    const unsigned char* hg = hb + nb * 64;
    #pragma unroll
    for (int jj = 0; jj < 4; ++jj) {
        int i = t + 256*jj;
        int row = i >> 3, c = i & 7;
        uint4 u = *(const uint4*)(hg + row*64 + c*16);
        uint2 lo; lo.x = u.x; lo.y = u.y;
        uint2 hi; hi.x = u.z; hi.y = u.w;
        *(uint2*)(&xh[row*XHP + c*4])     = lo;
        *(uint2*)(&xh[row*XHP + c*4 + 2]) = hi;
    }
    __syncthreads();
    int q = t >> 5, ng = t & 31;
    float tsv[4];
    #pragma unroll
    for (int i=0;i<4;++i) tsv[i] = ts[nb + ng + i*32];
    float acc[4][8];
    #pragma unroll
    for (int i=0;i<4;++i)
        #pragma unroll
        for (int j=0;j<8;++j) acc[i][j]=0.f;
    for (int kp = 0; kp < 16; kp += 2) {
        uint4 wA0 = *(const uint4*)(&wh[kp*64 + q*8]);
        uint4 wA1 = *(const uint4*)(&wh[kp*64 + q*8 + 4]);
        uint4 wB0 = *(const uint4*)(&wh[(kp+1)*64 + q*8]);
        uint4 wB1 = *(const uint4*)(&wh[(kp+1)*64 + q*8 + 4]);
        #pragma unroll
        for (int i=0;i<4;++i) {
            uint2 xv = *(const uint2*)(&xh[(ng + i*32)*XHP + kp]);
            acc[i][0]=fdot2u(xv.x, wA0.x, acc[i][0]);
            acc[i][1]=fdot2u(xv.x, wA0.y, acc[i][1]);
            acc[i][2]=fdot2u(xv.x, wA0.z, acc[i][2]);
            acc[i][3]=fdot2u(xv.x, wA0.w, acc[i][3]);
            acc[i][4]=fdot2u(xv.x, wA1.x, acc[i][4]);
            acc[i][5]=fdot2u(xv.x, wA1.y, acc[i][5]);
            acc[i][6]=fdot2u(xv.x, wA1.z, acc[i][6]);
            acc[i][7]=fdot2u(xv.x, wA1.w, acc[i][7]);
            acc[i][0]=fdot2u(xv.y, wB0.x, acc[i][0]);
            acc[i][1]=fdot2u(xv.y, wB0.y, acc[i][1]);
            acc[i][2]=fdot2u(xv.y, wB0.z, acc[i][2]);
            acc[i][3]=fdot2u(xv.y, wB0.w, acc[i][3]);
            acc[i][4]=fdot2u(xv.y, wB1.x, acc[i][4]);
            acc[i][5]=fdot2u(xv.y, wB1.y, acc[i][5]);
            acc[i][6]=fdot2u(xv.y, wB1.z, acc[i][6]);
            acc[i][7]=fdot2u(xv.y, wB1.w, acc[i][7]);
        }
    }
    if (q < 4) {
        #pragma unroll
        for (int i=0;i<4;++i) {
            float sc = tsv[i];
            uint4 pk;
            pk.x = packh2(acc[i][0]*sc, acc[i][1]*sc);
            pk.y = packh2(acc[i][2]*sc, acc[i][3]*sc);
            pk.z = packh2(acc[i][4]*sc, acc[i][5]*sc);
            pk.w = packh2(acc[i][6]*sc, acc[i][7]*sc);
            *(uint4*)(yb + (nb + ng + i*32)*64 + q*16) = pk;
        }
    } else {
        int qq = q - 4;
        float b0=bb[qq*8+0],b1=bb[qq*8+1],b2=bb[qq*8+2],b3=bb[qq*8+3];
        float b4=bb[qq*8+4],b5=bb[qq*8+5],b6=bb[qq*8+6],b7=bb[qq*8+7];
        #pragma unroll
        for (int i=0;i<4;++i) {
            float sc = tsv[i];
            uint4 pk;
            pk.x = packh2(acc[i][0]*sc+b0, acc[i][1]*sc+b1);
            pk.y = packh2(acc[i][2]*sc+b2, acc[i][3]*sc+b3);
            pk.z = packh2(acc[i][4]*sc+b4, acc[i][5]*sc+b5);
            pk.w = packh2(acc[i][6]*sc+b6, acc[i][7]*sc+b7);
            *(uint4*)(seedb + (nb + ng + i*32)*64 + qq*16) = pk;
        }
    }
}

// ---------- fused gather + relu + score ----------
__global__ __launch_bounds__(256) void k_gather(
    const int2* __restrict__ meta, const int2* __restrict__ edge_sorted,
    const unsigned char* __restrict__ yb, const float* __restrict__ pw,
    const int* __restrict__ mask, const unsigned char* __restrict__ seedb,
    unsigned char* __restrict__ hout, float* __restrict__ s)
{
    unsigned orig = blockIdx.x;
    unsigned nwg8 = gridDim.x >> 3;
    unsigned bid = (orig & 7u) * nwg8 + (orig >> 3);
    size_t tid = (size_t)bid * 256 + threadIdx.x;
    int node = (int)(tid >> 2);
    int q = (int)(tid & 3);                 // lane owns features 8q..8q+7
    float4 wv0 = ((const float4*)pw)[2*q];
    float4 wv1 = ((const float4*)pw)[2*q+1];
    float nn = wv0.x*wv0.x + wv0.y*wv0.y + wv0.z*wv0.z + wv0.w*wv0.w
             + wv1.x*wv1.x + wv1.y*wv1.y + wv1.z*wv1.z + wv1.w*wv1.w;
    nn += __shfl_xor(nn, 1); nn += __shfl_xor(nn, 2);
    float nrm = sqrtf(nn);
    bool valid = mask ? (mask[node] != 0) : true;
    float4 a0 = make_float4(0.f,0.f,0.f,0.f), a1 = make_float4(0.f,0.f,0.f,0.f);
    float4 b0 = make_float4(0.f,0.f,0.f,0.f), b1 = make_float4(0.f,0.f,0.f,0.f);
    if (valid) {
        uint4 su = *(const uint4*)(seedb + (size_t)node * 64 + q * 16);
        float2 s0 = unph2(su.x), s1 = unph2(su.y), s2 = unph2(su.z), s3 = unph2(su.w);
        a0 = make_float4(s0.x, s0.y, s1.x, s1.y);
        a1 = make_float4(s2.x, s2.y, s3.x, s3.y);
        #pragma unroll
        for (int p = 0; p < 2; ++p) {
            int2 m = meta[(size_t)p*NNODES + node];
            int e = m.x, end = m.x + m.y;
            for (; e + 1 < end; e += 2) {
                int2 ed0 = edge_sorted[e];
                int2 ed1 = edge_sorted[e+1];
                uint4 u0 = *(const uint4*)(yb + (size_t)ed0.x * 64 + q * 16);
                uint4 u1 = *(const uint4*)(yb + (size_t)ed1.x * 64 + q * 16);
                float w0 = __int_as_float(ed0.y);
                float w1 = __int_as_float(ed1.y);
                float2 p0, p1;
                p0 = unph2(u0.x); p1 = unph2(u0.y);
                a0.x = fmaf(p0.x, w0, a0.x); a0.y = fmaf(p0.y, w0, a0.y);
                a0.z = fmaf(p1.x, w0, a0.z); a0.w = fmaf(p1.y, w0, a0.w);
                p0 = unph2(u0.z); p1 = unph2(u0.w);
                a1.x = fmaf(p0.x, w0, a1.x); a1.y = fmaf(p0.y, w0, a1.y);
                a1.z = fmaf(p1.x, w0, a1.z); a1.w = fmaf(p1.y, w0, a1.w);
                p0 = unph2(u1.x); p1 = unph2(u1.y);
                b0.x = fmaf(p0.x, w1, b0.x); b0.y = fmaf(p0.y, w1, b0.y);
                b0.z = fmaf(p1.x, w1, b0.z); b0.w = fmaf(p1.y, w1, b0.w);
                p0 = unph2(u1.z); p1 = unph2(u1.w);
                b1.x = fmaf(p0.x, w1, b1.x); b1.y = fmaf(p0.y, w1, b1.y);
                b1.z = fmaf(p1.x, w1, b1.z); b1.w = fmaf(p1.y, w1, b1.w);
            }
            if (e < end) {
                int2 ed0 = edge_sorted[e];
                uint4 u0 = *(const uint4*)(yb + (size_t)ed0.x * 64 + q * 16);
                float w0 = __int_as_float(ed0.y);
                float2 p0, p1;
                p0 = unph2(u0.x); p1 = unph2(u0.y);
                a0.x = fmaf(p0.x, w0, a0.x); a0.y = fmaf(p0.y, w0, a0.y);
                a0.z = fmaf(p1.x, w0, a0.z); a0.w = fmaf(p1.y, w0, a0.w);
                p0 = unph2(u0.z); p1 = unph2(u0.w);
                a1.x = fmaf(p0.x, w0, a1.x); a1.y = fmaf(p0.y, w0, a1.y);
                a1.z = fmaf(p1.x, w0, a1.z); a1.w = fmaf(p1.y, w0, a1.w);
            }
        }
    }
    float hv0x = fmaxf(a0.x + b0.x, 0.f), hv0y = fmaxf(a0.y + b0.y, 0.f);
    float hv0z = fmaxf(a0.z + b0.z, 0.f), hv0w = fmaxf(a0.w + b0.w, 0.f);
    float hv1x = fmaxf(a1.x + b1.x, 0.f), hv1y = fmaxf(a1.y + b1.y, 0.f);
    float hv1z = fmaxf(a1.z + b1.z, 0.f), hv1w = fmaxf(a1.w + b1.w, 0.f);
    uint4 hw;
    hw.x = packh2(hv0x, hv0y);
    hw.y = packh2(hv0z, hv0w);
    hw.z = packh2(hv1x, hv1y);
    hw.w = packh2(hv1z, hv1w);
    *(uint4*)(hout + (size_t)node * 64 + q * 16) = hw;
    float dot = hv0x*wv0.x + hv0y*wv0.y + hv0z*wv0.z + hv0w*wv0.w
              + hv1x*wv1.x + hv1y*wv1.y + hv1z*wv1.z + hv1w*wv1.w;
    dot += __shfl_xor(dot, 1); dot += __shfl_xor(dot, 2);
    if (q == 0) s[node] = valid ? (dot / nrm) : -INFINITY;
}

// ---------- pooling: radix select + reduce; pool2 fuses the readout MLP ----------
__global__ __launch_bounds__(1024) void k_pool(
    const float* __restrict__ s, const unsigned char* __restrict__ hb,
    float* __restrict__ ts_out, int* __restrict__ mask_out,
    float* __restrict__ xout, int ksel,
    const float* __restrict__ x1, const float* __restrict__ l1W,
    const float* __restrict__ l1b, const float* __restrict__ l2W,
    const float* __restrict__ l2b, const float* __restrict__ l3W,
    const float* __restrict__ l3b, float* __restrict__ out, int do_read)
{
    __shared__ unsigned keys[NPG];
    __shared__ unsigned hist[256];
    __shared__ unsigned wpart[16];
    __shared__ unsigned char flag[NPG];
    __shared__ unsigned sh_bin, sh_krem;
    __shared__ float red[16*64];
    __shared__ float zb[64];
    __shared__ float a1b[32];
    __shared__ float a2b[16];
    int t = threadIdx.x;
    int g = blockIdx.x;
    int lane = t & 63, wv = t >> 6;
    const float* sg = s + (size_t)g * NPG;
    for (int i = t; i < NPG; i += 1024) {
        unsigned u = __float_as_uint(sg[i]);
        keys[i] = (u & 0x80000000u) ? ~u : (u | 0x80000000u);
    }
    __syncthreads();
    unsigned prefix = 0u;
    unsigned krem = (unsigned)ksel;
    for (int level = 0; level < 4; ++level) {
        int shift = 24 - 8*level;
        if (t < 256) hist[t] = 0u;
        __syncthreads();
        unsigned pmask = level ? (0xFFFFFFFFu << (shift + 8)) : 0u;
        for (int i = t; i < NPG; i += 1024) {
            unsigned key = keys[i];
            if ((key & pmask) == prefix)
                atomicAdd(&hist[(key >> shift) & 0xFFu], 1u);
        }
        __syncthreads();
        unsigned vv = 0, sc = 0;
        if (t < 256) {
            vv = hist[255 - t];
            sc = wscan_u(vv, lane);
            if (lane == 63) wpart[wv] = sc;
        }
        __syncthreads();
        if (t < 256) {
            unsigned bsum = 0;
            for (int i = 0; i < wv; ++i) bsum += wpart[i];
            unsigned incl = bsum + sc;
            unsigned excl = incl - vv;
            if (incl >= krem && excl < krem) {
                sh_bin = (unsigned)(255 - t);
                sh_krem = krem - excl;
            }
        }
        __syncthreads();
        prefix |= (sh_bin << shift);
        krem = sh_krem;
    }
    __syncthreads();
    unsigned T = prefix;
    unsigned ties = krem;
    int base = t * 2;
    unsigned k0 = keys[base], k1 = keys[base+1];
    unsigned ceq = (k0 == T ? 1u : 0u) + (k1 == T ? 1u : 0u);
    unsigned sc2 = wscan_u(ceq, lane);
    if (lane == 63) wpart[wv] = sc2;
    __syncthreads();
    unsigned bsum2 = 0;
    for (int i = 0; i < wv; ++i) bsum2 += wpart[i];
    unsigned run = bsum2 + sc2 - ceq;
    {
        unsigned char f0, f1;
        if (k0 > T) f0 = 1;
        else if (k0 == T) { f0 = (run < ties) ? 1 : 0; run++; }
        else f0 = 0;
        if (k1 > T) f1 = 1;
        else if (k1 == T) { f1 = (run < ties) ? 1 : 0; run++; }
        else f1 = 0;
        flag[base] = f0; flag[base+1] = f1;
    }
    __syncthreads();

    float mx[32], sm[32];
    #pragma unroll
    for (int j=0;j<32;++j){ mx[j]=-INFINITY; sm[j]=0.f; }
    const unsigned char* hg = hb + (size_t)g * NPG * 64;
    for (int i = t; i < NPG; i += 1024) {
        bool sel = flag[i] != 0;
        float tsv = sel ? tanhf(sg[i]) : 0.f;
        const uint4* hr = (const uint4*)(hg + (size_t)i*64);
        #pragma unroll
        for (int c4=0;c4<4;++c4) {
            uint4 u = hr[c4];
            float2 p0=unph2(u.x), p1=unph2(u.y), p2=unph2(u.z), p3=unph2(u.w);
            float vals[8] = {p0.x,p0.y,p1.x,p1.y,p2.x,p2.y,p3.x,p3.y};
            #pragma unroll
            for (int j=0;j<8;++j) {
                float v = vals[j]*tsv;
                if (sel) { mx[c4*8+j]=fmaxf(mx[c4*8+j],v); sm[c4*8+j]+=v; }
            }
        }
        if (ts_out) ts_out[(size_t)g*NPG + i] = tsv;
        if (mask_out) mask_out[(size_t)g*NPG + i] = sel ? 1 : 0;
    }
    #pragma unroll
    for (int j=0;j<32;++j) {
        for (int off=32; off; off>>=1) {
            mx[j] = fmaxf(mx[j], __shfl_xor(mx[j], off));
            sm[j] += __shfl_xor(sm[j], off);
        }
    }
    if (lane == 0) {
        #pragma unroll
        for (int j=0;j<32;++j) { red[wv*64 + j] = mx[j]; red[wv*64 + 32 + j] = sm[j]; }
    }
    __syncthreads();
    if (t < 32) {
        float m = red[t], ss = red[32 + t];
        #pragma unroll
        for (int w=1; w<16; ++w) { m = fmaxf(m, red[w*64 + t]); ss += red[w*64 + 32 + t]; }
        if (!do_read) {
            xout[(size_t)g*64 + t] = m;
            xout[(size_t)g*64 + 32 + t] = ss / (float)ksel;
        } else {
            zb[t]      = x1[(size_t)g*64 + t]      + m;
            zb[32 + t] = x1[(size_t)g*64 + 32 + t] + ss / (float)ksel;
        }
    }
    if (do_read) {
        __syncthreads();
        if (t < 32) {
            float acc = l1b[t];
            #pragma unroll
            for (int i=0;i<64;++i) acc = fmaf(zb[i], l1W[i*32+t], acc);
            a1b[t] = fmaxf(acc, 0.f);
        }
        __syncthreads();
        if (t < 16) {
            float acc = l2b[t];
            #pragma unroll
            for (int i=0;i<32;++i) acc = fmaf(a1b[i], l2W[i*16+t], acc);
            a2b[t] = fmaxf(acc, 0.f);
        }
        __syncthreads();
        if (t == 0) {
            float o0 = l3b[0], o1 = l3b[1];
            #pragma unroll
            for (int i=0;i<16;++i) {
                o0 = fmaf(a2b[i], l3W[i*2+0], o0);
                o1 = fmaf(a2b[i], l3W[i*2+1], o1);
            }
            float m2 = fmaxf(o0, o1);
            float lse = m2 + logf(expf(o0-m2) + expf(o1-m2));
            out[g*2+0] = o0 - lse;
            out[g*2+1] = o1 - lse;
        }
    }
}

extern "C" void kernel_launch(void* const* d_in, const int* in_sizes, int n_in,
                              void* d_out, int out_size, void* d_ws, size_t ws_size,
                              hipStream_t stream)
{
    const float* x      = (const float*)d_in[0];
    const int*   ei     = (const int*)d_in[1];   // int32 (JAX x64 disabled)
    const float* eattr  = (const float*)d_in[2];
    const float* W1rel  = (const float*)d_in[4];
    const float* b1     = (const float*)d_in[5];
    const float* W1root = (const float*)d_in[6];
    const float* p1w    = (const float*)d_in[7];
    const float* W2rel  = (const float*)d_in[8];
    const float* b2     = (const float*)d_in[9];
    const float* W2root = (const float*)d_in[10];
    const float* p2w    = (const float*)d_in[11];
    const float* l1W    = (const float*)d_in[12];
    const float* l1b    = (const float*)d_in[13];
    const float* l2W    = (const float*)d_in[14];
    const float* l2b    = (const float*)d_in[15];
    const float* l3W    = (const float*)d_in[16];
    const float* l3b    = (const float*)d_in[17];
    const int* srcp = ei;
    const int* dstp = ei + NEDGES;

    unsigned char* yb    = (unsigned char*)d_ws;      // [NNODES,32] fp16 (16 MB)
    unsigned char* seedb = yb + (size_t)NNODES*64;    // [NNODES,32] fp16 (16 MB)
    unsigned char* hb    = seedb + (size_t)NNODES*64; // [NNODES,32] fp16 (16 MB)
    float* s1   = (float*)(hb + (size_t)NNODES*64);   // [NNODES]
    float* ts   = s1 + NNODES;                        // [NNODES]
    int*   mask = (int*)(ts + NNODES);                // [NNODES]
    float* x1   = (float*)(mask + NNODES);            // [128,64]
    float* x2   = x1 + NGRAPH*64;                     // [128,64] (unused by pool2 now)
    int2*  meta = (int2*)(x2 + NGRAPH*64);            // [2*NNODES] (start,count)
    int2*  edge_sorted = (int2*)(meta + 2*NNODES);    // [NEDGES] (src, ew)
    float* out  = (float*)d_out;

    dim3 b256(256);
    // ---- partitioned CSR: 2 WGs per graph (LDS build, deterministic) ----
    k_csr<<<NGRAPH*2, dim3(1024), 0, stream>>>(srcp, dstp, eattr, meta,
                                               edge_sorted);
    // ---- conv1 front-end (dot2) + gather/score ----
    k_gemm64<<<NNODES/128, b256, 0, stream>>>(x, W1rel, W1root, b1, yb, seedb);
    k_gather<<<NNODES*4/256, b256, 0, stream>>>(meta, edge_sorted,
                                                yb, p1w, nullptr, seedb, hb, s1);
    // ---- pool1 (ts + mask + x1) ----
    k_pool<<<NGRAPH, dim3(1024), 0, stream>>>(s1, hb, ts, mask, x1, KSEL1,
                                              nullptr, nullptr, nullptr, nullptr,
                                              nullptr, nullptr, nullptr, nullptr, 0);
    // ---- conv2 front-end (dot2, ts fused) + gather/score ----
    k_gemm32<<<NNODES/128, b256, 0, stream>>>(hb, ts, W2rel, W2root, b2, yb, seedb);
    k_gather<<<NNODES*4/256, b256, 0, stream>>>(meta, edge_sorted,
                                                yb, p2w, mask, seedb, hb, s1);
    // ---- pool2 + fused readout MLP ----
    k_pool<<<NGRAPH, dim3(1024), 0, stream>>>(s1, hb, nullptr, nullptr, x2, KSEL2,
                                              x1, l1W, l1b, l2W, l2b, l3W, l3b,
                                              out, 1);
}

// Round 25
// 187.717 us; speedup vs baseline: 1.3156x; 1.0026x over previous
//
#include <hip/hip_runtime.h>
#include <hip/hip_fp16.h>
#include <math.h>

#define NNODES (128*2048)
#define NEDGES (NNODES*8)
#define NPG 2048
#define EPG (NPG*8)
#define HPG (EPG/2)          // 8192 edges per partition
#define NGRAPH 128
#define KSEL1 1639
#define KSEL2 1312

typedef _Float16 half2_t __attribute__((ext_vector_type(2)));

__device__ __forceinline__ unsigned packh2(float a, float b) {
    __half2 h = __floats2half2_rn(a, b);
    return *reinterpret_cast<unsigned*>(&h);
}
__device__ __forceinline__ float2 unph2(unsigned u) {
    __half2 h = *reinterpret_cast<__half2*>(&u);
    return __half22float2(h);
}
// fp16-pair dot with fp32 accumulate (v_dot2_f32_f16); exact fallback.
__device__ __forceinline__ float fdot2u(unsigned a, unsigned b, float c) {
#if __has_builtin(__builtin_amdgcn_fdot2)
    half2_t ha = *reinterpret_cast<half2_t*>(&a);
    half2_t hb = *reinterpret_cast<half2_t*>(&b);
    return __builtin_amdgcn_fdot2(ha, hb, c, false);
#else
    float2 fa = unph2(a), fb = unph2(b);
    return fmaf(fa.y, fb.y, fmaf(fa.x, fb.x, c));
#endif
}
__device__ __forceinline__ unsigned wscan_u(unsigned v, int lane) {
    #pragma unroll
    for (int off = 1; off < 64; off <<= 1) {
        unsigned n = __shfl_up(v, off);
        if (lane >= off) v += n;
    }
    return v;
}
__device__ __forceinline__ int wscan_i(int v, int lane) {
    #pragma unroll
    for (int off = 1; off < 64; off <<= 1) {
        int n = __shfl_up(v, off);
        if (lane >= off) v += n;
    }
    return v;
}

// ---------- partitioned CSR build, fully in LDS (deterministic) ----------
// Packed u16 histogram (76.1 KB LDS -> 2 WGs/CU). meta is interleaved:
// meta2[node*2 + part] = (start, count) so gather fetches both parts in
// one int4 load.
__global__ __launch_bounds__(1024) void k_csr(
    const int* __restrict__ src, const int* __restrict__ dst,
    const float* __restrict__ ew, int2* __restrict__ meta2,
    int2* __restrict__ edge_sorted)
{
    __shared__ int2 ebuf[HPG];     // 64 KB
    __shared__ int cntp[NPG/2];    // 4 KB (two u16 counts per int)
    __shared__ int curs[NPG];      // 8 KB
    __shared__ int wpart[16];
    int t = threadIdx.x;
    int lane = t & 63, wv = t >> 6;
    int bid = blockIdx.x;
    int g = bid >> 1, part = bid & 1;
    const int ebase = g * EPG + part * HPG;
    int ds[8], ss[8]; float wws[8];
    #pragma unroll
    for (int j=0;j<8;++j) {
        int idx = ebase + t + 1024*j;
        ds[j] = dst[idx] & (NPG-1);
        ss[j] = src[idx];
        wws[j] = ew[idx];
    }
    for (int i = t; i < NPG/2; i += 1024) cntp[i] = 0;
    __syncthreads();
    #pragma unroll
    for (int j=0;j<8;++j)
        atomicAdd(&cntp[ds[j] >> 1], 1 << ((ds[j] & 1) * 16));
    __syncthreads();
    int base = t * 2;
    int pc = cntp[t];
    int l0 = pc & 0xFFFF, l1 = (pc >> 16) & 0xFFFF;
    int s0 = l0 + l1;
    int sc = wscan_i(s0, lane);
    if (lane == 63) wpart[wv] = sc;
    __syncthreads();
    int b = 0;
    for (int i = 0; i < wv; ++i) b += wpart[i];
    int run = b + sc - s0;
    curs[base] = run; curs[base+1] = run + l0;
    __syncthreads();
    for (int i = t; i < NPG; i += 1024) {
        int cv = (cntp[i >> 1] >> ((i & 1) * 16)) & 0xFFFF;
        meta2[(size_t)(g*NPG + i) * 2 + part] = make_int2(ebase + curs[i], cv);
    }
    __syncthreads();
    #pragma unroll
    for (int j=0;j<8;++j) {
        int pos = atomicAdd(&curs[ds[j]], 1);
        ebuf[pos] = make_int2(ss[j], __float_as_int(wws[j]));
    }
    __syncthreads();
    // canonical per-bucket order (insertion sort in LDS)
    for (int i = t; i < NPG; i += 1024) {
        int cv = (cntp[i >> 1] >> ((i & 1) * 16)) & 0xFFFF;
        if (cv > 1) {
            int beg = curs[i] - cv;              // curs[i] is now start+cnt
            for (int a = 1; a < cv; ++a) {
                int2 key = ebuf[beg + a];
                unsigned long long kk =
                    ((unsigned long long)(unsigned)key.x << 32) | (unsigned)key.y;
                int p = beg + a - 1;
                while (p >= beg) {
                    int2 cur = ebuf[p];
                    unsigned long long ck =
                        ((unsigned long long)(unsigned)cur.x << 32) | (unsigned)cur.y;
                    if (ck <= kk) break;
                    ebuf[p + 1] = cur;
                    --p;
                }
                ebuf[p + 1] = key;
            }
        }
    }
    __syncthreads();
    #pragma unroll
    for (int j=0;j<8;++j) {
        int i = t + 1024*j;
        edge_sorted[ebase + i] = ebuf[i];
    }
}

// ---------- conv1 front-end: fp16-pair dot2, single staging pass ----------
#define XHP 34
__global__ __launch_bounds__(256, 4) void k_gemm64(
    const float* __restrict__ x, const float* __restrict__ Wrel,
    const float* __restrict__ Wroot, const float* __restrict__ b,
    unsigned char* __restrict__ yb, unsigned char* __restrict__ seedb)
{
    __shared__ unsigned xh[128*XHP];   // 17.4 KB
    __shared__ unsigned wh[32*64];     // 8 KB
    __shared__ float bb[32];
    int t = threadIdx.x;
    for (int i = t; i < 32*64; i += 256) {
        int kp = i >> 6, j = i & 63;
        float wa = (j < 32) ? Wrel[(2*kp)*32 + j]   : Wroot[(2*kp)*32 + (j-32)];
        float wb = (j < 32) ? Wrel[(2*kp+1)*32 + j] : Wroot[(2*kp+1)*32 + (j-32)];
        wh[i] = packh2(wa, wb);
    }
    if (t < 32) bb[t] = b[t];
    size_t nb = (size_t)blockIdx.x * 128;
    {
        const float4* xg4 = (const float4*)(x + nb*64);
        #pragma unroll
        for (int jj = 0; jj < 8; ++jj) {
            int i = t + 256*jj;
            int row = i >> 4, c = i & 15;
            float4 v = xg4[i];
            uint2 pk;
            pk.x = packh2(v.x, v.y);
            pk.y = packh2(v.z, v.w);
            *(uint2*)(&xh[row*XHP + c*2]) = pk;
        }
    }
    __syncthreads();
    int q = t >> 5, ng = t & 31;
    float acc[4][8];
    #pragma unroll
    for (int i=0;i<4;++i)
        #pragma unroll
        for (int j=0;j<8;++j) acc[i][j]=0.f;
    for (int kp = 0; kp < 32; kp += 2) {
        uint4 wA0 = *(const uint4*)(&wh[kp*64 + q*8]);
        uint4 wA1 = *(const uint4*)(&wh[kp*64 + q*8 + 4]);
        uint4 wB0 = *(const uint4*)(&wh[(kp+1)*64 + q*8]);
        uint4 wB1 = *(const uint4*)(&wh[(kp+1)*64 + q*8 + 4]);
        #pragma unroll
        for (int i=0;i<4;++i) {
            uint2 xv = *(const uint2*)(&xh[(ng + i*32)*XHP + kp]);
            acc[i][0]=fdot2u(xv.x, wA0.x, acc[i][0]);
            acc[i][1]=fdot2u(xv.x, wA0.y, acc[i][1]);
            acc[i][2]=fdot2u(xv.x, wA0.z, acc[i][2]);
            acc[i][3]=fdot2u(xv.x, wA0.w, acc[i][3]);
            acc[i][4]=fdot2u(xv.x, wA1.x, acc[i][4]);
            acc[i][5]=fdot2u(xv.x, wA1.y, acc[i][5]);
            acc[i][6]=fdot2u(xv.x, wA1.z, acc[i][6]);
            acc[i][7]=fdot2u(xv.x, wA1.w, acc[i][7]);
            acc[i][0]=fdot2u(xv.y, wB0.x, acc[i][0]);
            acc[i][1]=fdot2u(xv.y, wB0.y, acc[i][1]);
            acc[i][2]=fdot2u(xv.y, wB0.z, acc[i][2]);
            acc[i][3]=fdot2u(xv.y, wB0.w, acc[i][3]);
            acc[i][4]=fdot2u(xv.y, wB1.x, acc[i][4]);
            acc[i][5]=fdot2u(xv.y, wB1.y, acc[i][5]);
            acc[i][6]=fdot2u(xv.y, wB1.z, acc[i][6]);
            acc[i][7]=fdot2u(xv.y, wB1.w, acc[i][7]);
        }
    }
    if (q < 4) {               // y outputs (fp16), wave-uniform branch
        #pragma unroll
        for (int i=0;i<4;++i) {
            uint4 pk;
            pk.x = packh2(acc[i][0], acc[i][1]);
            pk.y = packh2(acc[i][2], acc[i][3]);
            pk.z = packh2(acc[i][4], acc[i][5]);
            pk.w = packh2(acc[i][6], acc[i][7]);
            *(uint4*)(yb + (nb + ng + i*32)*64 + q*16) = pk;
        }
    } else {
        int qq = q - 4;
        float b0=bb[qq*8+0],b1=bb[qq*8+1],b2=bb[qq*8+2],b3=bb[qq*8+3];
        float b4=bb[qq*8+4],b5=bb[qq*8+5],b6=bb[qq*8+6],b7=bb[qq*8+7];
        #pragma unroll
        for (int i=0;i<4;++i) {
            uint4 pk;
            pk.x = packh2(acc[i][0]+b0, acc[i][1]+b1);
            pk.y = packh2(acc[i][2]+b2, acc[i][3]+b3);
            pk.z = packh2(acc[i][4]+b4, acc[i][5]+b5);
            pk.w = packh2(acc[i][6]+b6, acc[i][7]+b7);
            *(uint4*)(seedb + (nb + ng + i*32)*64 + qq*16) = pk;
        }
    }
}

// ---------- conv2 front-end: h fp16 (already paired), dot2; ts folded ----------
__global__ __launch_bounds__(256, 4) void k_gemm32(
    const unsigned char* __restrict__ hb, const float* __restrict__ ts,
    const float* __restrict__ Wrel, const float* __restrict__ Wroot,
    const float* __restrict__ b, unsigned char* __restrict__ yb,
    unsigned char* __restrict__ seedb)
{
    __shared__ unsigned xh[128*XHP];   // 17.4 KB
    __shared__ unsigned wh[16*64];     // 4 KB
    __shared__ float bb[32];
    int t = threadIdx.x;
    for (int i = t; i < 16*64; i += 256) {
        int kp = i >> 6, j = i & 63;
        float wa = (j < 32) ? Wrel[(2*kp)*32 + j]   : Wroot[(2*kp)*32 + (j-32)];
        float wb = (j < 32) ? Wrel[(2*kp+1)*32 + j] : Wroot[(2*kp+1)*32 + (j-32)];
        wh[i] = packh2(wa, wb);
    }
    if (t < 32) bb[t] = b[t];
    size_t nb = (size_t)blockIdx.x * 128;
    const unsigned char* hg = hb + nb * 64;
    #pragma unroll
    for (int jj = 0; jj < 4; ++jj) {
        int i = t + 256*jj;
        int row = i >> 3, c = i & 7;
        uint4 u = *(const uint4*)(hg + row*64 + c*16);
        uint2 lo; lo.x = u.x; lo.y = u.y;
        uint2 hi; hi.x = u.z; hi.y = u.w;
        *(uint2*)(&xh[row*XHP + c*4])     = lo;
        *(uint2*)(&xh[row*XHP + c*4 + 2]) = hi;
    }
    __syncthreads();
    int q = t >> 5, ng = t & 31;
    float tsv[4];
    #pragma unroll
    for (int i=0;i<4;++i) tsv[i] = ts[nb + ng + i*32];
    float acc[4][8];
    #pragma unroll
    for (int i=0;i<4;++i)
        #pragma unroll
        for (int j=0;j<8;++j) acc[i][j]=0.f;
    for (int kp = 0; kp < 16; kp += 2) {
        uint4 wA0 = *(const uint4*)(&wh[kp*64 + q*8]);
        uint4 wA1 = *(const uint4*)(&wh[kp*64 + q*8 + 4]);
        uint4 wB0 = *(const uint4*)(&wh[(kp+1)*64 + q*8]);
        uint4 wB1 = *(const uint4*)(&wh[(kp+1)*64 + q*8 + 4]);
        #pragma unroll
        for (int i=0;i<4;++i) {
            uint2 xv = *(const uint2*)(&xh[(ng + i*32)*XHP + kp]);
            acc[i][0]=fdot2u(xv.x, wA0.x, acc[i][0]);
            acc[i][1]=fdot2u(xv.x, wA0.y, acc[i][1]);
            acc[i][2]=fdot2u(xv.x, wA0.z, acc[i][2]);
            acc[i][3]=fdot2u(xv.x, wA0.w, acc[i][3]);
            acc[i][4]=fdot2u(xv.x, wA1.x, acc[i][4]);
            acc[i][5]=fdot2u(xv.x, wA1.y, acc[i][5]);
            acc[i][6]=fdot2u(xv.x, wA1.z, acc[i][6]);
            acc[i][7]=fdot2u(xv.x, wA1.w, acc[i][7]);
            acc[i][0]=fdot2u(xv.y, wB0.x, acc[i][0]);
            acc[i][1]=fdot2u(xv.y, wB0.y, acc[i][1]);
            acc[i][2]=fdot2u(xv.y, wB0.z, acc[i][2]);
            acc[i][3]=fdot2u(xv.y, wB0.w, acc[i][3]);
            acc[i][4]=fdot2u(xv.y, wB1.x, acc[i][4]);
            acc[i][5]=fdot2u(xv.y, wB1.y, acc[i][5]);
            acc[i][6]=fdot2u(xv.y, wB1.z, acc[i][6]);
            acc[i][7]=fdot2u(xv.y, wB1.w, acc[i][7]);
        }
    }
    if (q < 4) {
        #pragma unroll
        for (int i=0;i<4;++i) {
            float sc = tsv[i];
            uint4 pk;
            pk.x = packh2(acc[i][0]*sc, acc[i][1]*sc);
            pk.y = packh2(acc[i][2]*sc, acc[i][3]*sc);
            pk.z = packh2(acc[i][4]*sc, acc[i][5]*sc);
            pk.w = packh2(acc[i][6]*sc, acc[i][7]*sc);
            *(uint4*)(yb + (nb + ng + i*32)*64 + q*16) = pk;
        }
    } else {
        int qq = q - 4;
        float b0=bb[qq*8+0],b1=bb[qq*8+1],b2=bb[qq*8+2],b3=bb[qq*8+3];
        float b4=bb[qq*8+4],b5=bb[qq*8+5],b6=bb[qq*8+6],b7=bb[qq*8+7];
        #pragma unroll
        for (int i=0;i<4;++i) {
            float sc = tsv[i];
            uint4 pk;
            pk.x = packh2(acc[i][0]*sc+b0, acc[i][1]*sc+b1);
            pk.y = packh2(acc[i][2]*sc+b2, acc[i][3]*sc+b3);
            pk.z = packh2(acc[i][4]*sc+b4, acc[i][5]*sc+b5);
            pk.w = packh2(acc[i][6]*sc+b6, acc[i][7]*sc+b7);
            *(uint4*)(seedb + (nb + ng + i*32)*64 + qq*16) = pk;
        }
    }
}

// ---------- fused gather + relu + score ----------
// 4 lanes per node, uint4 (16 B) y loads; both partition descriptors
// fetched with ONE int4 load (meta interleaved). XCD-aware swizzle.
__global__ __launch_bounds__(256) void k_gather(
    const int2* __restrict__ meta2, const int2* __restrict__ edge_sorted,
    const unsigned char* __restrict__ yb, const float* __restrict__ pw,
    const int* __restrict__ mask, const unsigned char* __restrict__ seedb,
    unsigned char* __restrict__ hout, float* __restrict__ s)
{
    unsigned orig = blockIdx.x;
    unsigned nwg8 = gridDim.x >> 3;
    unsigned bid = (orig & 7u) * nwg8 + (orig >> 3);
    size_t tid = (size_t)bid * 256 + threadIdx.x;
    int node = (int)(tid >> 2);
    int q = (int)(tid & 3);                 // lane owns features 8q..8q+7
    float4 wv0 = ((const float4*)pw)[2*q];
    float4 wv1 = ((const float4*)pw)[2*q+1];
    float nn = wv0.x*wv0.x + wv0.y*wv0.y + wv0.z*wv0.z + wv0.w*wv0.w
             + wv1.x*wv1.x + wv1.y*wv1.y + wv1.z*wv1.z + wv1.w*wv1.w;
    nn += __shfl_xor(nn, 1); nn += __shfl_xor(nn, 2);
    float nrm = sqrtf(nn);
    bool valid = mask ? (mask[node] != 0) : true;
    float4 a0 = make_float4(0.f,0.f,0.f,0.f), a1 = make_float4(0.f,0.f,0.f,0.f);
    float4 b0 = make_float4(0.f,0.f,0.f,0.f), b1 = make_float4(0.f,0.f,0.f,0.f);
    if (valid) {
        uint4 su = *(const uint4*)(seedb + (size_t)node * 64 + q * 16);
        float2 s0 = unph2(su.x), s1 = unph2(su.y), s2 = unph2(su.z), s3 = unph2(su.w);
        a0 = make_float4(s0.x, s0.y, s1.x, s1.y);
        a1 = make_float4(s2.x, s2.y, s3.x, s3.y);
        int4 m4 = *(const int4*)(&meta2[(size_t)node * 2]);
        int es[2], ee[2];
        es[0] = m4.x; ee[0] = m4.x + m4.y;
        es[1] = m4.z; ee[1] = m4.z + m4.w;
        #pragma unroll
        for (int p = 0; p < 2; ++p) {
            int e = es[p], end = ee[p];
            for (; e + 1 < end; e += 2) {
                int2 ed0 = edge_sorted[e];
                int2 ed1 = edge_sorted[e+1];
                uint4 u0 = *(const uint4*)(yb + (size_t)ed0.x * 64 + q * 16);
                uint4 u1 = *(const uint4*)(yb + (size_t)ed1.x * 64 + q * 16);
                float w0 = __int_as_float(ed0.y);
                float w1 = __int_as_float(ed1.y);
                float2 p0, p1;
                p0 = unph2(u0.x); p1 = unph2(u0.y);
                a0.x = fmaf(p0.x, w0, a0.x); a0.y = fmaf(p0.y, w0, a0.y);
                a0.z = fmaf(p1.x, w0, a0.z); a0.w = fmaf(p1.y, w0, a0.w);
                p0 = unph2(u0.z); p1 = unph2(u0.w);
                a1.x = fmaf(p0.x, w0, a1.x); a1.y = fmaf(p0.y, w0, a1.y);
                a1.z = fmaf(p1.x, w0, a1.z); a1.w = fmaf(p1.y, w0, a1.w);
                p0 = unph2(u1.x); p1 = unph2(u1.y);
                b0.x = fmaf(p0.x, w1, b0.x); b0.y = fmaf(p0.y, w1, b0.y);
                b0.z = fmaf(p1.x, w1, b0.z); b0.w = fmaf(p1.y, w1, b0.w);
                p0 = unph2(u1.z); p1 = unph2(u1.w);
                b1.x = fmaf(p0.x, w1, b1.x); b1.y = fmaf(p0.y, w1, b1.y);
                b1.z = fmaf(p1.x, w1, b1.z); b1.w = fmaf(p1.y, w1, b1.w);
            }
            if (e < end) {
                int2 ed0 = edge_sorted[e];
                uint4 u0 = *(const uint4*)(yb + (size_t)ed0.x * 64 + q * 16);
                float w0 = __int_as_float(ed0.y);
                float2 p0, p1;
                p0 = unph2(u0.x); p1 = unph2(u0.y);
                a0.x = fmaf(p0.x, w0, a0.x); a0.y = fmaf(p0.y, w0, a0.y);
                a0.z = fmaf(p1.x, w0, a0.z); a0.w = fmaf(p1.y, w0, a0.w);
                p0 = unph2(u0.z); p1 = unph2(u0.w);
                a1.x = fmaf(p0.x, w0, a1.x); a1.y = fmaf(p0.y, w0, a1.y);
                a1.z = fmaf(p1.x, w0, a1.z); a1.w = fmaf(p1.y, w0, a1.w);
            }
        }
    }
    float hv0x = fmaxf(a0.x + b0.x, 0.f), hv0y = fmaxf(a0.y + b0.y, 0.f);
    float hv0z = fmaxf(a0.z + b0.z, 0.f), hv0w = fmaxf(a0.w + b0.w, 0.f);
    float hv1x = fmaxf(a1.x + b1.x, 0.f), hv1y = fmaxf(a1.y + b1.y, 0.f);
    float hv1z = fmaxf(a1.z + b1.z, 0.f), hv1w = fmaxf(a1.w + b1.w, 0.f);
    uint4 hw;
    hw.x = packh2(hv0x, hv0y);
    hw.y = packh2(hv0z, hv0w);
    hw.z = packh2(hv1x, hv1y);
    hw.w = packh2(hv1z, hv1w);
    *(uint4*)(hout + (size_t)node * 64 + q * 16) = hw;
    float dot = hv0x*wv0.x + hv0y*wv0.y + hv0z*wv0.z + hv0w*wv0.w
              + hv1x*wv1.x + hv1y*wv1.y + hv1z*wv1.z + hv1w*wv1.w;
    dot += __shfl_xor(dot, 1); dot += __shfl_xor(dot, 2);
    if (q == 0) s[node] = valid ? (dot / nrm) : -INFINITY;
}

// ---------- pooling: radix select + reduce; pool2 fuses the readout MLP ----------
__global__ __launch_bounds__(1024) void k_pool(
    const float* __restrict__ s, const unsigned char* __restrict__ hb,
    float* __restrict__ ts_out, int* __restrict__ mask_out,
    float* __restrict__ xout, int ksel,
    const float* __restrict__ x1, const float* __restrict__ l1W,
    const float* __restrict__ l1b, const float* __restrict__ l2W,
    const float* __restrict__ l2b, const float* __restrict__ l3W,
    const float* __restrict__ l3b, float* __restrict__ out, int do_read)
{
    __shared__ unsigned keys[NPG];
    __shared__ unsigned hist[256];
    __shared__ unsigned wpart[16];
    __shared__ unsigned char flag[NPG];
    __shared__ unsigned sh_bin, sh_krem;
    __shared__ float red[16*64];
    __shared__ float zb[64];
    __shared__ float a1b[32];
    __shared__ float a2b[16];
    int t = threadIdx.x;
    int g = blockIdx.x;
    int lane = t & 63, wv = t >> 6;
    const float* sg = s + (size_t)g * NPG;
    for (int i = t; i < NPG; i += 1024) {
        unsigned u = __float_as_uint(sg[i]);
        keys[i] = (u & 0x80000000u) ? ~u : (u | 0x80000000u);
    }
    __syncthreads();
    unsigned prefix = 0u;
    unsigned krem = (unsigned)ksel;
    for (int level = 0; level < 4; ++level) {
        int shift = 24 - 8*level;
        if (t < 256) hist[t] = 0u;
        __syncthreads();
        unsigned pmask = level ? (0xFFFFFFFFu << (shift + 8)) : 0u;
        for (int i = t; i < NPG; i += 1024) {
            unsigned key = keys[i];
            if ((key & pmask) == prefix)
                atomicAdd(&hist[(key >> shift) & 0xFFu], 1u);
        }
        __syncthreads();
        unsigned vv = 0, sc = 0;
        if (t < 256) {
            vv = hist[255 - t];
            sc = wscan_u(vv, lane);
            if (lane == 63) wpart[wv] = sc;
        }
        __syncthreads();
        if (t < 256) {
            unsigned bsum = 0;
            for (int i = 0; i < wv; ++i) bsum += wpart[i];
            unsigned incl = bsum + sc;
            unsigned excl = incl - vv;
            if (incl >= krem && excl < krem) {
                sh_bin = (unsigned)(255 - t);
                sh_krem = krem - excl;
            }
        }
        __syncthreads();
        prefix |= (sh_bin << shift);
        krem = sh_krem;
    }
    __syncthreads();
    unsigned T = prefix;
    unsigned ties = krem;
    int base = t * 2;
    unsigned k0 = keys[base], k1 = keys[base+1];
    unsigned ceq = (k0 == T ? 1u : 0u) + (k1 == T ? 1u : 0u);
    unsigned sc2 = wscan_u(ceq, lane);
    if (lane == 63) wpart[wv] = sc2;
    __syncthreads();
    unsigned bsum2 = 0;
    for (int i = 0; i < wv; ++i) bsum2 += wpart[i];
    unsigned run = bsum2 + sc2 - ceq;
    {
        unsigned char f0, f1;
        if (k0 > T) f0 = 1;
        else if (k0 == T) { f0 = (run < ties) ? 1 : 0; run++; }
        else f0 = 0;
        if (k1 > T) f1 = 1;
        else if (k1 == T) { f1 = (run < ties) ? 1 : 0; run++; }
        else f1 = 0;
        flag[base] = f0; flag[base+1] = f1;
    }
    __syncthreads();

    float mx[32], sm[32];
    #pragma unroll
    for (int j=0;j<32;++j){ mx[j]=-INFINITY; sm[j]=0.f; }
    const unsigned char* hg = hb + (size_t)g * NPG * 64;
    for (int i = t; i < NPG; i += 1024) {
        bool sel = flag[i] != 0;
        float tsv = sel ? tanhf(sg[i]) : 0.f;
        const uint4* hr = (const uint4*)(hg + (size_t)i*64);
        #pragma unroll
        for (int c4=0;c4<4;++c4) {
            uint4 u = hr[c4];
            float2 p0=unph2(u.x), p1=unph2(u.y), p2=unph2(u.z), p3=unph2(u.w);
            float vals[8] = {p0.x,p0.y,p1.x,p1.y,p2.x,p2.y,p3.x,p3.y};
            #pragma unroll
            for (int j=0;j<8;++j) {
                float v = vals[j]*tsv;
                if (sel) { mx[c4*8+j]=fmaxf(mx[c4*8+j],v); sm[c4*8+j]+=v; }
            }
        }
        if (ts_out) ts_out[(size_t)g*NPG + i] = tsv;
        if (mask_out) mask_out[(size_t)g*NPG + i] = sel ? 1 : 0;
    }
    #pragma unroll
    for (int j=0;j<32;++j) {
        for (int off=32; off; off>>=1) {
            mx[j] = fmaxf(mx[j], __shfl_xor(mx[j], off));
            sm[j] += __shfl_xor(sm[j], off);
        }
    }
    if (lane == 0) {
        #pragma unroll
        for (int j=0;j<32;++j) { red[wv*64 + j] = mx[j]; red[wv*64 + 32 + j] = sm[j]; }
    }
    __syncthreads();
    if (t < 32) {
        float m = red[t], ss = red[32 + t];
        #pragma unroll
        for (int w=1; w<16; ++w) { m = fmaxf(m, red[w*64 + t]); ss += red[w*64 + 32 + t]; }
        if (!do_read) {
            xout[(size_t)g*64 + t] = m;
            xout[(size_t)g*64 + 32 + t] = ss / (float)ksel;
        } else {
            zb[t]      = x1[(size_t)g*64 + t]      + m;
            zb[32 + t] = x1[(size_t)g*64 + 32 + t] + ss / (float)ksel;
        }
    }
    if (do_read) {
        __syncthreads();
        if (t < 32) {
            float acc = l1b[t];
            #pragma unroll
            for (int i=0;i<64;++i) acc = fmaf(zb[i], l1W[i*32+t], acc);
            a1b[t] = fmaxf(acc, 0.f);
        }
        __syncthreads();
        if (t < 16) {
            float acc = l2b[t];
            #pragma unroll
            for (int i=0;i<32;++i) acc = fmaf(a1b[i], l2W[i*16+t], acc);
            a2b[t] = fmaxf(acc, 0.f);
        }
        __syncthreads();
        if (t == 0) {
            float o0 = l3b[0], o1 = l3b[1];
            #pragma unroll
            for (int i=0;i<16;++i) {
                o0 = fmaf(a2b[i], l3W[i*2+0], o0);
                o1 = fmaf(a2b[i], l3W[i*2+1], o1);
            }
            float m2 = fmaxf(o0, o1);
            float lse = m2 + logf(expf(o0-m2) + expf(o1-m2));
            out[g*2+0] = o0 - lse;
            out[g*2+1] = o1 - lse;
        }
    }
}

extern "C" void kernel_launch(void* const* d_in, const int* in_sizes, int n_in,
                              void* d_out, int out_size, void* d_ws, size_t ws_size,
                              hipStream_t stream)
{
    const float* x      = (const float*)d_in[0];
    const int*   ei     = (const int*)d_in[1];   // int32 (JAX x64 disabled)
    const float* eattr  = (const float*)d_in[2];
    const float* W1rel  = (const float*)d_in[4];
    const float* b1     = (const float*)d_in[5];
    const float* W1root = (const float*)d_in[6];
    const float* p1w    = (const float*)d_in[7];
    const float* W2rel  = (const float*)d_in[8];
    const float* b2     = (const float*)d_in[9];
    const float* W2root = (const float*)d_in[10];
    const float* p2w    = (const float*)d_in[11];
    const float* l1W    = (const float*)d_in[12];
    const float* l1b    = (const float*)d_in[13];
    const float* l2W    = (const float*)d_in[14];
    const float* l2b    = (const float*)d_in[15];
    const float* l3W    = (const float*)d_in[16];
    const float* l3b    = (const float*)d_in[17];
    const int* srcp = ei;
    const int* dstp = ei + NEDGES;

    unsigned char* yb    = (unsigned char*)d_ws;      // [NNODES,32] fp16 (16 MB)
    unsigned char* seedb = yb + (size_t)NNODES*64;    // [NNODES,32] fp16 (16 MB)
    unsigned char* hb    = seedb + (size_t)NNODES*64; // [NNODES,32] fp16 (16 MB)
    float* s1   = (float*)(hb + (size_t)NNODES*64);   // [NNODES]
    float* ts   = s1 + NNODES;                        // [NNODES]
    int*   mask = (int*)(ts + NNODES);                // [NNODES]
    float* x1   = (float*)(mask + NNODES);            // [128,64]
    float* x2   = x1 + NGRAPH*64;                     // [128,64] (scratch)
    int2*  meta2 = (int2*)(x2 + NGRAPH*64);           // [2*NNODES] interleaved
    int2*  edge_sorted = (int2*)(meta2 + 2*NNODES);   // [NEDGES] (src, ew)
    float* out  = (float*)d_out;

    dim3 b256(256);
    // ---- partitioned CSR: 2 WGs per graph (LDS build, deterministic) ----
    k_csr<<<NGRAPH*2, dim3(1024), 0, stream>>>(srcp, dstp, eattr, meta2,
                                               edge_sorted);
    // ---- conv1 front-end (dot2) + gather/score ----
    k_gemm64<<<NNODES/128, b256, 0, stream>>>(x, W1rel, W1root, b1, yb, seedb);
    k_gather<<<NNODES*4/256, b256, 0, stream>>>(meta2, edge_sorted,
                                                yb, p1w, nullptr, seedb, hb, s1);
    // ---- pool1 (ts + mask + x1) ----
    k_pool<<<NGRAPH, dim3(1024), 0, stream>>>(s1, hb, ts, mask, x1, KSEL1,
                                              nullptr, nullptr, nullptr, nullptr,
                                              nullptr, nullptr, nullptr, nullptr, 0);
    // ---- conv2 front-end (dot2, ts fused) + gather/score ----
    k_gemm32<<<NNODES/128, b256, 0, stream>>>(hb, ts, W2rel, W2root, b2, yb, seedb);
    k_gather<<<NNODES*4/256, b256, 0, stream>>>(meta2, edge_sorted,
                                                yb, p2w, mask, seedb, hb, s1);
    // ---- pool2 + fused readout MLP ----
    k_pool<<<NGRAPH, dim3(1024), 0, stream>>>(s1, hb, nullptr, nullptr, x2, KSEL2,
                                              x1, l1W, l1b, l2W, l2b, l3W, l3b,
                                              out, 1);
}